// Round 3
// baseline (4426.415 us; speedup 1.0000x reference)
//
#include <hip/hip_runtime.h>

typedef unsigned short u16;
typedef __bf16 bf16x8 __attribute__((ext_vector_type(8)));
typedef float f32x4 __attribute__((ext_vector_type(4)));

__device__ __forceinline__ float b2f(u16 h) {
    union { unsigned u; float f; } v; v.u = ((unsigned)h) << 16; return v.f;
}
__device__ __forceinline__ u16 f2b(float f) {
    union { float f; unsigned u; } v; v.f = f;
    unsigned r = v.u + 0x7FFF + ((v.u >> 16) & 1);
    return (u16)(r >> 16);
}
__device__ __forceinline__ float sigm(float x) { return 1.f / (1.f + __expf(-x)); }

// wcol[p] = OUT_MASK[PERM[p]] : wigner row (fwd) / wigner_inv col (bwd) for permuted slot p
__constant__ int d_wcol[19]    = {0,2,6,12,20, 3,7,13,21, 1,5,11,19, 8,14,22, 4,10,18};
// rad offset (in the 3072-wide radial vector) for permuted slot p
__constant__ int d_radbase[19] = {0,256,512,768,1024, 1280,1536,1792,2048, 1280,1536,1792,2048,
                                  2304,2560,2816, 2304,2560,2816};
// gate channel base (l-1)*128 for permuted slot p (p=0 uses silu instead)
__constant__ int d_gbase[19]   = {0, 0,128,256,384, 0,128,256,384, 0,128,256,384,
                                  128,256,384, 128,256,384};

// ---------------------------------------------------------------------------
// bf16 MFMA GEMM:  C[M,N] = A[M,K] @ B[N,K]^T (+fp32 bias),  128x128 tile.
// ---------------------------------------------------------------------------
__global__ __launch_bounds__(256)
void gemm_bf16(const u16* __restrict__ A, int lda,
               const u16* __restrict__ B, int ldb,
               const float* __restrict__ bias,
               u16* __restrict__ C, int ldc,
               int M, int NT, int MT, int K)
{
    __shared__ u16 As[128][72];  // +8 pad: conflict-free b128 frag reads
    __shared__ u16 Bs[128][72];
    int w = blockIdx.x;
    int g = w & 7, q = w >> 3;
    int mt = g + 8 * (q / NT);
    int nt = q % NT;
    if (mt >= MT) return;
    int m0 = mt * 128, n0 = nt * 128;
    int tid = threadIdx.x;
    int lane = tid & 63, wave = tid >> 6;
    int wm = (wave >> 1) * 64, wn = (wave & 1) * 64;

    f32x4 acc[4][4] = {};

    for (int k0 = 0; k0 < K; k0 += 64) {
        #pragma unroll
        for (int i = 0; i < 4; ++i) {
            int chunk = tid + i * 256;          // 1024 chunks of 8 bf16
            int row = chunk >> 3, col = (chunk & 7) * 8;
            int ga = m0 + row; if (ga > M - 1) ga = M - 1;   // clamp (rows >= M unused)
            *(uint4*)&As[row][col] = *(const uint4*)(A + (size_t)ga * lda + k0 + col);
            *(uint4*)&Bs[row][col] = *(const uint4*)(B + (size_t)(n0 + row) * ldb + k0 + col);
        }
        __syncthreads();
        #pragma unroll
        for (int kk = 0; kk < 64; kk += 32) {
            bf16x8 af[4], bfr[4];
            int kof = kk + (lane >> 4) * 8;
            #pragma unroll
            for (int t = 0; t < 4; ++t) {
                af[t]  = *(const bf16x8*)&As[wm + t * 16 + (lane & 15)][kof];
                bfr[t] = *(const bf16x8*)&Bs[wn + t * 16 + (lane & 15)][kof];
            }
            #pragma unroll
            for (int mi = 0; mi < 4; ++mi)
                #pragma unroll
                for (int ni = 0; ni < 4; ++ni)
                    acc[mi][ni] = __builtin_amdgcn_mfma_f32_16x16x32_bf16(
                        af[mi], bfr[ni], acc[mi][ni], 0, 0, 0);
        }
        __syncthreads();
    }

    #pragma unroll
    for (int ni = 0; ni < 4; ++ni) {
        int col = n0 + wn + ni * 16 + (lane & 15);
        float bv = bias ? bias[col] : 0.f;
        #pragma unroll
        for (int mi = 0; mi < 4; ++mi) {
            int rb = m0 + wm + mi * 16 + (lane >> 4) * 4;
            #pragma unroll
            for (int r = 0; r < 4; ++r) {
                int row = rb + r;
                if (row < M) C[(size_t)row * ldc + col] = f2b(acc[mi][ni][r] + bv);
            }
        }
    }
}

// ---------------------------------------------------------------------------
// Radial stage 1 (fp32 in): h = x_edge @ W_r1^T + b ; LayerNorm ; silu -> bf16
// Edge identity taken through perm (sorted-by-dst order).
// ---------------------------------------------------------------------------
__global__ __launch_bounds__(128)
void radial1(const float* __restrict__ xe, const int* __restrict__ perm,
             int c0, const float* __restrict__ W1,
             const float* __restrict__ b1, const float* __restrict__ lg,
             const float* __restrict__ lb, u16* __restrict__ sh)
{
    __shared__ float xs[128];
    __shared__ float part[4];
    int e = blockIdx.x, c = threadIdx.x;
    int pe = perm[c0 + e];
    xs[c] = xe[(size_t)pe * 128 + c];
    __syncthreads();
    float acc = 0.f;
    const float4* wr = (const float4*)(W1 + (size_t)c * 128);
    #pragma unroll
    for (int kb = 0; kb < 32; ++kb) {
        float4 v = wr[kb];
        acc += v.x * xs[kb * 4 + 0];
        acc += v.y * xs[kb * 4 + 1];
        acc += v.z * xs[kb * 4 + 2];
        acc += v.w * xs[kb * 4 + 3];
    }
    float h = acc + b1[c];
    float s = h, ss = h * h;
    #pragma unroll
    for (int o = 32; o > 0; o >>= 1) {
        s  += __shfl_down(s, o, 64);
        ss += __shfl_down(ss, o, 64);
    }
    int wv = c >> 6;
    if ((c & 63) == 0) { part[wv * 2] = s; part[wv * 2 + 1] = ss; }
    __syncthreads();
    float S = part[0] + part[2], SS = part[1] + part[3];
    float mu = S * (1.f / 128.f);
    float var = SS * (1.f / 128.f) - mu * mu;
    float hn = (h - mu) * rsqrtf(var + 1e-5f) * lg[c] + lb[c];
    sh[(size_t)e * 128 + c] = f2b(hn * sigm(hn));
}

// ---------------------------------------------------------------------------
// Gather src/dst fp32 features, apply wigner[OUT_MASK] rows in PERM order,
// scale by radial (bf16), write conv1 input Xc1 (n x 4864 bf16).
// 1 wave/edge, 4 edges/block; perm indirection (sorted-by-dst order).
// ---------------------------------------------------------------------------
__global__ __launch_bounds__(256, 4)
void wigner_gather(const float* __restrict__ x, const float* __restrict__ wig,
                   const u16* __restrict__ rad, const int* __restrict__ eidx,
                   const int* __restrict__ perm,
                   u16* __restrict__ Xc1, int E, int c0, int n)
{
    __shared__ float wgs[4][25 * 24 + 8];   // j-major: [wave][j*24 + p]
    int wave = threadIdx.x >> 6, lane = threadIdx.x & 63;
    int e = blockIdx.x * 4 + wave;
    if (e > n - 1) e = n - 1;               // tail waves redo edge n-1 (benign identical writes)
    int pe = perm[c0 + e];

    // stage wigner rows transposed to j-major (pad p to 24 for aligned b128)
    const float* wp = wig + (size_t)pe * 625;
    float* wg = wgs[wave];
    for (int i = lane; i < 600; i += 64) {
        int j = i / 24, p = i - j * 24;
        wg[i] = (p < 19) ? wp[d_wcol[p] * 25 + j] : 0.f;
    }

    int s = eidx[pe], dn = eidx[E + pe];
    const float* xbase = (lane < 32)
        ? x + (size_t)s  * 3200 + lane * 4
        : x + (size_t)dn * 3200 + (lane - 32) * 4;

    __syncthreads();

    float4 acc[20];
    #pragma unroll
    for (int p = 0; p < 20; ++p) acc[p] = make_float4(0.f, 0.f, 0.f, 0.f);

    float4 nxt = *(const float4*)xbase;
    #pragma unroll
    for (int j = 0; j < 25; ++j) {
        float4 xv = nxt;
        if (j < 24) nxt = *(const float4*)(xbase + (j + 1) * 128);
        #pragma unroll
        for (int pb = 0; pb < 5; ++pb) {
            float4 w4 = *(const float4*)&wg[j * 24 + pb * 4];
            int q = pb * 4;
            acc[q+0].x += w4.x * xv.x; acc[q+0].y += w4.x * xv.y;
            acc[q+0].z += w4.x * xv.z; acc[q+0].w += w4.x * xv.w;
            acc[q+1].x += w4.y * xv.x; acc[q+1].y += w4.y * xv.y;
            acc[q+1].z += w4.y * xv.z; acc[q+1].w += w4.y * xv.w;
            acc[q+2].x += w4.z * xv.x; acc[q+2].y += w4.z * xv.y;
            acc[q+2].z += w4.z * xv.z; acc[q+2].w += w4.z * xv.w;
            acc[q+3].x += w4.w * xv.x; acc[q+3].y += w4.w * xv.y;
            acc[q+3].z += w4.w * xv.z; acc[q+3].w += w4.w * xv.w;
        }
    }

    int c4v = lane * 4;
    const u16* rp = rad + (size_t)e * 3072;
    u16* outp = Xc1 + (size_t)e * 4864 + c4v;
    #pragma unroll
    for (int p = 0; p < 19; ++p) {
        ushort4 rv = *(const ushort4*)(rp + d_radbase[p] + c4v);
        ushort4 st;
        st.x = f2b(acc[p].x * b2f(rv.x));
        st.y = f2b(acc[p].y * b2f(rv.y));
        st.z = f2b(acc[p].z * b2f(rv.z));
        st.w = f2b(acc[p].w * b2f(rv.w));
        *(ushort4*)(outp + (size_t)p * 256) = st;
    }
}

// ---------------------------------------------------------------------------
// Gate: slot0 -> silu, slots 1..18 -> * sigmoid(extra[(l-1)*128+c]).
// ---------------------------------------------------------------------------
__global__ __launch_bounds__(256)
void gate_combine(const u16* __restrict__ Yc1, u16* __restrict__ Xc2)
{
    int e = blockIdx.x;
    const u16* yp = Yc1 + (size_t)e * 2944;
    u16* xp = Xc2 + (size_t)e * 2432;
    for (int r = threadIdx.x; r < 2432; r += 256) {
        int p = r >> 7, c = r & 127;
        float v = b2f(yp[512 + r]);
        float o;
        if (p == 0) o = v * sigm(v);
        else        o = v * sigm(b2f(yp[d_gbase[p] + c]));
        xp[r] = f2b(o);
    }
}

// ---------------------------------------------------------------------------
// Final: edges sorted by dst -> one wave per NODE. Iterate the node's
// edges within this chunk, accumulate env * (winv[:, :, OUT_MASK] @ msg)
// in registers, single NON-ATOMIC read-add-write of the node row.
// No block barriers (waves fully independent; per-wave LDS tile, DS in-order).
// ---------------------------------------------------------------------------
__global__ __launch_bounds__(256)
void final_node(const u16* __restrict__ Yc2, const float* __restrict__ winv,
                const float* __restrict__ edist, const int* __restrict__ perm,
                const int* __restrict__ row_ptr, float* __restrict__ out,
                int c0, int c1, int Nn)
{
    __shared__ float wis[4][25 * 24 + 8];   // [wave][i*24 + p]
    int wave = threadIdx.x >> 6, lane = threadIdx.x & 63;
    int v = blockIdx.x * 4 + wave;
    if (v >= Nn) return;
    int beg = row_ptr[v], end = row_ptr[v + 1];
    if (beg < c0) beg = c0;
    if (end > c1) end = c1;
    if (beg >= end) return;

    float* wi = wis[wave];
    // fixed per-lane staging pattern: lane covers idx = lane + 64k, k<10
    int soff[10];
    #pragma unroll
    for (int k = 0; k < 10; ++k) {
        int idx = lane + k * 64;
        int i = idx / 24, p = idx - i * 24;
        bool act = (idx < 600) && (p < 19);
        soff[k] = act ? (i * 25 + d_wcol[p]) : -1;
        if (idx < 600 && p >= 19) wi[idx] = 0.f;   // zero pad once (DS in-order)
    }

    int cc = lane * 2;
    float2 acc[25];
    #pragma unroll
    for (int i = 0; i < 25; ++i) acc[i] = make_float2(0.f, 0.f);

    for (int pos = beg; pos < end; ++pos) {
        int pe = perm[pos];
        const float* wp = winv + (size_t)pe * 625;
        #pragma unroll
        for (int k = 0; k < 10; ++k)
            if (soff[k] >= 0) wi[lane + k * 64] = wp[soff[k]];

        float d = edist[pe] * (1.f / 6.f);
        float d2 = d * d, d5 = d2 * d2 * d;
        float env = (d < 1.f) ? (1.f + d5 * (-21.f + 35.f * d - 15.f * d2)) : 0.f;

        const u16* yp = Yc2 + (size_t)(pos - c0) * 2432 + cc;
        float2 pv[20];
        #pragma unroll
        for (int p = 0; p < 19; ++p) {
            unsigned u = *(const unsigned*)(yp + (size_t)p * 128);
            pv[p].x = b2f((u16)(u & 0xffff)) * env;
            pv[p].y = b2f((u16)(u >> 16)) * env;
        }
        pv[19] = make_float2(0.f, 0.f);

        #pragma unroll
        for (int i = 0; i < 25; ++i) {
            float ax = 0.f, ay = 0.f;
            #pragma unroll
            for (int pb = 0; pb < 5; ++pb) {
                float4 wv = *(const float4*)&wi[i * 24 + pb * 4];
                float2 q0 = pv[pb * 4], q1 = pv[pb * 4 + 1];
                float2 q2 = pv[pb * 4 + 2], q3 = pv[pb * 4 + 3];
                ax += wv.x * q0.x + wv.y * q1.x + wv.z * q2.x + wv.w * q3.x;
                ay += wv.x * q0.y + wv.y * q1.y + wv.z * q2.y + wv.w * q3.y;
            }
            acc[i].x += ax; acc[i].y += ay;
        }
    }

    float* ob = out + (size_t)v * 3200 + cc;
    #pragma unroll
    for (int i = 0; i < 25; ++i) {
        ob[i * 128]     += acc[i].x;      // exclusive owner: non-atomic RMW
        ob[i * 128 + 1] += acc[i].y;
    }
}

// ---------------------------------------------------------------------------
// Counting sort by dst: histogram -> single-block scan -> scatter.
// ---------------------------------------------------------------------------
__global__ __launch_bounds__(256)
void hist_k(const int* __restrict__ eidx, const int* __restrict__ noff,
            int* __restrict__ cnt, int E)
{
    int e = blockIdx.x * 256 + threadIdx.x;
    if (e < E) atomicAdd(&cnt[eidx[E + e] - noff[0]], 1);
}

__global__ __launch_bounds__(256)
void scan_k(const int* __restrict__ cnt, int* __restrict__ row_ptr,
            int* __restrict__ ofs, int Nn)
{
    __shared__ int part[256];
    int t = threadIdx.x;
    int per = (Nn + 255) / 256;
    int beg = t * per;
    int s = 0;
    for (int i = 0; i < per; ++i) {
        int idx = beg + i;
        if (idx < Nn) s += cnt[idx];
    }
    part[t] = s;
    __syncthreads();
    for (int o = 1; o < 256; o <<= 1) {
        int v = (t >= o) ? part[t - o] : 0;
        __syncthreads();
        part[t] += v;
        __syncthreads();
    }
    int run = (t == 0) ? 0 : part[t - 1];
    for (int i = 0; i < per; ++i) {
        int idx = beg + i;
        if (idx < Nn) {
            row_ptr[idx] = run;
            ofs[idx] = run;
            run += cnt[idx];
        }
    }
    if (t == 255) row_ptr[Nn] = part[255];
}

__global__ __launch_bounds__(256)
void scat_k(const int* __restrict__ eidx, const int* __restrict__ noff,
            int* __restrict__ ofs, int* __restrict__ perm, int E)
{
    int e = blockIdx.x * 256 + threadIdx.x;
    if (e < E) {
        int v = eidx[E + e] - noff[0];
        int pos = atomicAdd(&ofs[v], 1);
        perm[pos] = e;
    }
}

// ---------------------------------------------------------------------------
// Complex-fold weight transform (fp32 -> bf16)
// ---------------------------------------------------------------------------
__global__ __launch_bounds__(256)
void wprime(const float* __restrict__ Wm, u16* __restrict__ Wp, int H, int Kin)
{
    int o = blockIdx.y;
    int k = blockIdx.x * 256 + threadIdx.x;
    if (k >= 2 * Kin) return;
    float v;
    if (k < Kin) v = Wm[(size_t)o * Kin + k];
    else {
        int k2 = k - Kin;
        v = (o < H) ? -Wm[(size_t)(o + H) * Kin + k2]
                    :  Wm[(size_t)(o - H) * Kin + k2];
    }
    Wp[(size_t)o * 2 * Kin + k] = f2b(v);
}

__global__ __launch_bounds__(256)
void cvt_w(const float* __restrict__ a, u16* __restrict__ o, int n)
{
    int i = blockIdx.x * 256 + threadIdx.x;
    if (i < n) o[i] = f2b(a[i]);
}

__global__ __launch_bounds__(256)
void zerof(float4* __restrict__ p, int n4)
{
    int i = blockIdx.x * 256 + threadIdx.x;
    if (i < n4) p[i] = make_float4(0.f, 0.f, 0.f, 0.f);
}

extern "C" void kernel_launch(void* const* d_in, const int* in_sizes, int n_in,
                              void* d_out, int out_size, void* d_ws, size_t ws_size,
                              hipStream_t stream)
{
    const float* x      = (const float*)d_in[0];
    const float* x_edge = (const float*)d_in[1];
    const float* edist  = (const float*)d_in[2];
    const float* wig    = (const float*)d_in[3];
    const float* winv   = (const float*)d_in[4];
    const float* W_r1   = (const float*)d_in[5];
    const float* b_r1   = (const float*)d_in[6];
    const float* ln_g   = (const float*)d_in[7];
    const float* ln_b   = (const float*)d_in[8];
    const float* W_r2   = (const float*)d_in[9];
    const float* b_r2   = (const float*)d_in[10];
    const float* W0_1   = (const float*)d_in[11];
    const float* b0_1   = (const float*)d_in[12];
    const float* Wm1_1  = (const float*)d_in[13];
    const float* Wm2_1  = (const float*)d_in[14];
    const float* W0_2   = (const float*)d_in[15];
    const float* b0_2   = (const float*)d_in[16];
    const float* Wm1_2  = (const float*)d_in[17];
    const float* Wm2_2  = (const float*)d_in[18];
    const int*   eidx   = (const int*)d_in[19];
    const int*   noff   = (const int*)d_in[20];
    float* out = (float*)d_out;

    const int E  = in_sizes[2];          // 50000
    const int Nn = in_sizes[0] / 3200;   // nodes: x is Nn*25*128 ELEMENTS (in_sizes are element counts)

    size_t off = 0;
    auto take = [&](size_t bytes) -> char* {
        char* p = (char*)d_ws + off;
        off += (bytes + 255) & ~(size_t)255;
        return p;
    };
    // ---- fixed: bf16 weight copies (~14.4 MB) + sort structures ----
    u16* Wr2c = (u16*)take((size_t)3072 * 128 * 2);
    u16* W01c = (u16*)take((size_t)1152 * 1280 * 2);
    u16* Wp11 = (u16*)take((size_t)1024 * 2048 * 2);
    u16* Wp21 = (u16*)take((size_t)768 * 1536 * 2);
    u16* W02c = (u16*)take((size_t)640 * 640 * 2);
    u16* Wp12 = (u16*)take((size_t)1024 * 1024 * 2);
    u16* Wp22 = (u16*)take((size_t)768 * 768 * 2);
    int  NnR  = (Nn + 3) & ~3;
    int* cnt     = (int*)take((size_t)NnR * 4);
    int* ofs     = (int*)take((size_t)NnR * 4);
    int* row_ptr = (int*)take((size_t)(Nn + 1) * 4);
    int* perm    = (int*)take((size_t)E * 4);
    size_t fixed = off;

    // ---- adaptive chunk: 22016 B/edge, capped at 12800 edges ----
    const size_t per_edge = 256 + 6144 + 9728 + 5888;
    size_t avail = (ws_size > fixed + 65536) ? (ws_size - fixed - 65536) : 0;
    long long ch = (long long)(avail / per_edge);
    if (ch > 12800) ch = 12800;
    ch &= ~255LL;
    if (ch < 256) ch = 256;
    const int CH = (int)ch;

    u16* silu_h = (u16*)take((size_t)CH * 128 * 2);
    u16* radb   = (u16*)take((size_t)CH * 3072 * 2);
    u16* xreg   = (u16*)take((size_t)CH * 4864 * 2);  // Xc1, then Xc2
    u16* yreg   = (u16*)take((size_t)CH * 2944 * 2);  // Yc1, then Yc2

    dim3 b256(256);

    cvt_w<<<1536, b256, 0, stream>>>(W_r2, Wr2c, 3072 * 128);
    cvt_w<<<5760, b256, 0, stream>>>(W0_1, W01c, 1152 * 1280);
    cvt_w<<<1600, b256, 0, stream>>>(W0_2, W02c, 640 * 640);
    wprime<<<dim3(8, 1024), b256, 0, stream>>>(Wm1_1, Wp11, 512, 1024);
    wprime<<<dim3(6,  768), b256, 0, stream>>>(Wm2_1, Wp21, 384, 768);
    wprime<<<dim3(4, 1024), b256, 0, stream>>>(Wm1_2, Wp12, 512, 512);
    wprime<<<dim3(3,  768), b256, 0, stream>>>(Wm2_2, Wp22, 384, 384);

    zerof<<<(out_size / 4 + 255) / 256, b256, 0, stream>>>((float4*)out,
                                                           out_size / 4);

    // ---- counting sort of edges by dst ----
    zerof<<<(NnR / 4 + 255) / 256, b256, 0, stream>>>((float4*)cnt, NnR / 4);
    hist_k<<<(E + 255) / 256, b256, 0, stream>>>(eidx, noff, cnt, E);
    scan_k<<<1, b256, 0, stream>>>(cnt, row_ptr, ofs, Nn);
    scat_k<<<(E + 255) / 256, b256, 0, stream>>>(eidx, noff, ofs, perm, E);

    for (int c0 = 0; c0 < E; c0 += CH) {
        int n  = (E - c0 < CH) ? (E - c0) : CH;
        int MT = (n + 127) / 128;
        int gm = 8 * ((MT + 7) / 8);

        radial1<<<n, 128, 0, stream>>>(x_edge, perm, c0, W_r1, b_r1,
                                       ln_g, ln_b, silu_h);
        gemm_bf16<<<gm * 24, b256, 0, stream>>>(silu_h, 128, Wr2c, 128, b_r2,
                                                radb, 3072, n, 24, MT, 128);

        wigner_gather<<<(n + 3) / 4, b256, 0, stream>>>(x, wig, radb, eidx,
                                                        perm, xreg, E, c0, n);

        gemm_bf16<<<gm * 9, b256, 0, stream>>>(xreg,        4864, W01c, 1280, b0_1,
                                               yreg,        2944, n, 9, MT, 1280);
        gemm_bf16<<<gm * 8, b256, 0, stream>>>(xreg + 1280, 4864, Wp11, 2048, nullptr,
                                               yreg + 1152, 2944, n, 8, MT, 2048);
        gemm_bf16<<<gm * 6, b256, 0, stream>>>(xreg + 3328, 4864, Wp21, 1536, nullptr,
                                               yreg + 2176, 2944, n, 6, MT, 1536);

        gate_combine<<<n, b256, 0, stream>>>(yreg, xreg);

        gemm_bf16<<<gm * 5, b256, 0, stream>>>(xreg,        2432, W02c,  640, b0_2,
                                               yreg,        2432, n, 5, MT, 640);
        gemm_bf16<<<gm * 8, b256, 0, stream>>>(xreg + 640,  2432, Wp12, 1024, nullptr,
                                               yreg + 640,  2432, n, 8, MT, 1024);
        gemm_bf16<<<gm * 6, b256, 0, stream>>>(xreg + 1664, 2432, Wp22,  768, nullptr,
                                               yreg + 1664, 2432, n, 6, MT, 768);

        final_node<<<(Nn + 3) / 4, b256, 0, stream>>>(yreg, winv, edist, perm,
                                                      row_ptr, out, c0, c0 + n, Nn);
    }
}

// Round 4
// 3728.162 us; speedup vs baseline: 1.1873x; 1.1873x over previous
//
#include <hip/hip_runtime.h>

typedef unsigned short u16;
typedef __bf16 bf16x8 __attribute__((ext_vector_type(8)));
typedef float f32x4 __attribute__((ext_vector_type(4)));

__device__ __forceinline__ float b2f(u16 h) {
    union { unsigned u; float f; } v; v.u = ((unsigned)h) << 16; return v.f;
}
__device__ __forceinline__ u16 f2b(float f) {
    union { float f; unsigned u; } v; v.f = f;
    unsigned r = v.u + 0x7FFF + ((v.u >> 16) & 1);
    return (u16)(r >> 16);
}
__device__ __forceinline__ float sigm(float x) { return 1.f / (1.f + __expf(-x)); }

// wcol[p] = OUT_MASK[PERM[p]] : wigner row (fwd) / wigner_inv col (bwd) for permuted slot p
__constant__ int d_wcol[19]    = {0,2,6,12,20, 3,7,13,21, 1,5,11,19, 8,14,22, 4,10,18};
// rad offset (in the 3072-wide radial vector) for permuted slot p
__constant__ int d_radbase[19] = {0,256,512,768,1024, 1280,1536,1792,2048, 1280,1536,1792,2048,
                                  2304,2560,2816, 2304,2560,2816};
// gate channel base (l-1)*128 for permuted slot p (p=0 uses silu instead)
__constant__ int d_gbase[19]   = {0, 0,128,256,384, 0,128,256,384, 0,128,256,384,
                                  128,256,384, 128,256,384};

// ---------------------------------------------------------------------------
// bf16 MFMA GEMM:  C[M,N] = A[M,K] @ B[N,K]^T (+fp32 bias),  128x128 tile.
// ---------------------------------------------------------------------------
__global__ __launch_bounds__(256)
void gemm_bf16(const u16* __restrict__ A, int lda,
               const u16* __restrict__ B, int ldb,
               const float* __restrict__ bias,
               u16* __restrict__ C, int ldc,
               int M, int NT, int MT, int K)
{
    __shared__ u16 As[128][72];  // +8 pad: conflict-free b128 frag reads
    __shared__ u16 Bs[128][72];
    int w = blockIdx.x;
    int g = w & 7, q = w >> 3;
    int mt = g + 8 * (q / NT);
    int nt = q % NT;
    if (mt >= MT) return;
    int m0 = mt * 128, n0 = nt * 128;
    int tid = threadIdx.x;
    int lane = tid & 63, wave = tid >> 6;
    int wm = (wave >> 1) * 64, wn = (wave & 1) * 64;

    f32x4 acc[4][4] = {};

    for (int k0 = 0; k0 < K; k0 += 64) {
        #pragma unroll
        for (int i = 0; i < 4; ++i) {
            int chunk = tid + i * 256;          // 1024 chunks of 8 bf16
            int row = chunk >> 3, col = (chunk & 7) * 8;
            int ga = m0 + row; if (ga > M - 1) ga = M - 1;   // clamp (rows >= M unused)
            *(uint4*)&As[row][col] = *(const uint4*)(A + (size_t)ga * lda + k0 + col);
            *(uint4*)&Bs[row][col] = *(const uint4*)(B + (size_t)(n0 + row) * ldb + k0 + col);
        }
        __syncthreads();
        #pragma unroll
        for (int kk = 0; kk < 64; kk += 32) {
            bf16x8 af[4], bfr[4];
            int kof = kk + (lane >> 4) * 8;
            #pragma unroll
            for (int t = 0; t < 4; ++t) {
                af[t]  = *(const bf16x8*)&As[wm + t * 16 + (lane & 15)][kof];
                bfr[t] = *(const bf16x8*)&Bs[wn + t * 16 + (lane & 15)][kof];
            }
            #pragma unroll
            for (int mi = 0; mi < 4; ++mi)
                #pragma unroll
                for (int ni = 0; ni < 4; ++ni)
                    acc[mi][ni] = __builtin_amdgcn_mfma_f32_16x16x32_bf16(
                        af[mi], bfr[ni], acc[mi][ni], 0, 0, 0);
        }
        __syncthreads();
    }

    #pragma unroll
    for (int ni = 0; ni < 4; ++ni) {
        int col = n0 + wn + ni * 16 + (lane & 15);
        float bv = bias ? bias[col] : 0.f;
        #pragma unroll
        for (int mi = 0; mi < 4; ++mi) {
            int rb = m0 + wm + mi * 16 + (lane >> 4) * 4;
            #pragma unroll
            for (int r = 0; r < 4; ++r) {
                int row = rb + r;
                if (row < M) C[(size_t)row * ldc + col] = f2b(acc[mi][ni][r] + bv);
            }
        }
    }
}

// ---------------------------------------------------------------------------
// Radial stage 1 (fp32 in): h = x_edge @ W_r1^T + b ; LayerNorm ; silu -> bf16
// Edge identity taken through perm (sorted-by-dst order).
// ---------------------------------------------------------------------------
__global__ __launch_bounds__(128)
void radial1(const float* __restrict__ xe, const int* __restrict__ perm,
             int c0, const float* __restrict__ W1,
             const float* __restrict__ b1, const float* __restrict__ lg,
             const float* __restrict__ lb, u16* __restrict__ sh)
{
    __shared__ float xs[128];
    __shared__ float part[4];
    int e = blockIdx.x, c = threadIdx.x;
    int pe = perm[c0 + e];
    xs[c] = xe[(size_t)pe * 128 + c];
    __syncthreads();
    float acc = 0.f;
    const float4* wr = (const float4*)(W1 + (size_t)c * 128);
    #pragma unroll
    for (int kb = 0; kb < 32; ++kb) {
        float4 v = wr[kb];
        acc += v.x * xs[kb * 4 + 0];
        acc += v.y * xs[kb * 4 + 1];
        acc += v.z * xs[kb * 4 + 2];
        acc += v.w * xs[kb * 4 + 3];
    }
    float h = acc + b1[c];
    float s = h, ss = h * h;
    #pragma unroll
    for (int o = 32; o > 0; o >>= 1) {
        s  += __shfl_down(s, o, 64);
        ss += __shfl_down(ss, o, 64);
    }
    int wv = c >> 6;
    if ((c & 63) == 0) { part[wv * 2] = s; part[wv * 2 + 1] = ss; }
    __syncthreads();
    float S = part[0] + part[2], SS = part[1] + part[3];
    float mu = S * (1.f / 128.f);
    float var = SS * (1.f / 128.f) - mu * mu;
    float hn = (h - mu) * rsqrtf(var + 1e-5f) * lg[c] + lb[c];
    sh[(size_t)e * 128 + c] = f2b(hn * sigm(hn));
}

// ---------------------------------------------------------------------------
// Gather src/dst fp32 features, apply wigner[OUT_MASK] rows in PERM order,
// scale by radial (bf16), write conv1 input Xc1 (n x 4864 bf16).
// 1 wave/edge, 4 edges/block; perm indirection (sorted-by-dst order).
// ---------------------------------------------------------------------------
__global__ __launch_bounds__(256, 4)
void wigner_gather(const float* __restrict__ x, const float* __restrict__ wig,
                   const u16* __restrict__ rad, const int* __restrict__ eidx,
                   const int* __restrict__ perm,
                   u16* __restrict__ Xc1, int E, int c0, int n)
{
    __shared__ float wgs[4][25 * 24 + 8];   // j-major: [wave][j*24 + p]
    int wave = threadIdx.x >> 6, lane = threadIdx.x & 63;
    int e = blockIdx.x * 4 + wave;
    if (e > n - 1) e = n - 1;               // tail waves redo edge n-1 (benign identical writes)
    int pe = perm[c0 + e];

    // stage wigner rows transposed to j-major (pad p to 24 for aligned b128)
    const float* wp = wig + (size_t)pe * 625;
    float* wg = wgs[wave];
    for (int i = lane; i < 600; i += 64) {
        int j = i / 24, p = i - j * 24;
        wg[i] = (p < 19) ? wp[d_wcol[p] * 25 + j] : 0.f;
    }

    int s = eidx[pe], dn = eidx[E + pe];
    const float* xbase = (lane < 32)
        ? x + (size_t)s  * 3200 + lane * 4
        : x + (size_t)dn * 3200 + (lane - 32) * 4;

    __syncthreads();

    float4 acc[20];
    #pragma unroll
    for (int p = 0; p < 20; ++p) acc[p] = make_float4(0.f, 0.f, 0.f, 0.f);

    float4 nxt = *(const float4*)xbase;
    #pragma unroll
    for (int j = 0; j < 25; ++j) {
        float4 xv = nxt;
        if (j < 24) nxt = *(const float4*)(xbase + (j + 1) * 128);
        #pragma unroll
        for (int pb = 0; pb < 5; ++pb) {
            float4 w4 = *(const float4*)&wg[j * 24 + pb * 4];
            int q = pb * 4;
            acc[q+0].x += w4.x * xv.x; acc[q+0].y += w4.x * xv.y;
            acc[q+0].z += w4.x * xv.z; acc[q+0].w += w4.x * xv.w;
            acc[q+1].x += w4.y * xv.x; acc[q+1].y += w4.y * xv.y;
            acc[q+1].z += w4.y * xv.z; acc[q+1].w += w4.y * xv.w;
            acc[q+2].x += w4.z * xv.x; acc[q+2].y += w4.z * xv.y;
            acc[q+2].z += w4.z * xv.z; acc[q+2].w += w4.z * xv.w;
            acc[q+3].x += w4.w * xv.x; acc[q+3].y += w4.w * xv.y;
            acc[q+3].z += w4.w * xv.z; acc[q+3].w += w4.w * xv.w;
        }
    }

    int c4v = lane * 4;
    const u16* rp = rad + (size_t)e * 3072;
    u16* outp = Xc1 + (size_t)e * 4864 + c4v;
    #pragma unroll
    for (int p = 0; p < 19; ++p) {
        ushort4 rv = *(const ushort4*)(rp + d_radbase[p] + c4v);
        ushort4 st;
        st.x = f2b(acc[p].x * b2f(rv.x));
        st.y = f2b(acc[p].y * b2f(rv.y));
        st.z = f2b(acc[p].z * b2f(rv.z));
        st.w = f2b(acc[p].w * b2f(rv.w));
        *(ushort4*)(outp + (size_t)p * 256) = st;
    }
}

// ---------------------------------------------------------------------------
// Gate: slot0 -> silu, slots 1..18 -> * sigmoid(extra[(l-1)*128+c]).
// ---------------------------------------------------------------------------
__global__ __launch_bounds__(256)
void gate_combine(const u16* __restrict__ Yc1, u16* __restrict__ Xc2)
{
    int e = blockIdx.x;
    const u16* yp = Yc1 + (size_t)e * 2944;
    u16* xp = Xc2 + (size_t)e * 2432;
    for (int r = threadIdx.x; r < 2432; r += 256) {
        int p = r >> 7, c = r & 127;
        float v = b2f(yp[512 + r]);
        float o;
        if (p == 0) o = v * sigm(v);
        else        o = v * sigm(b2f(yp[d_gbase[p] + c]));
        xp[r] = f2b(o);
    }
}

// ---------------------------------------------------------------------------
// Final v4: 5 waves per node, each owning 5 output rows (i = g*5..g*5+4).
// Edges sorted by dst; each wave iterates its node's edges in this chunk,
// accumulates env * (winv[rows, OUT_MASK] @ msg) in registers, then does a
// non-atomic RMW of its exclusive row slice. 5x the wave parallelism of v3
// (v3: 0.6 waves/SIMD, VALUBusy 6.5% -> latency-bound).
// ---------------------------------------------------------------------------
__global__ __launch_bounds__(256)
void final_node(const u16* __restrict__ Yc2, const float* __restrict__ winv,
                const float* __restrict__ edist, const int* __restrict__ perm,
                const int* __restrict__ row_ptr, float* __restrict__ out,
                int c0, int c1, int Nn)
{
    __shared__ float wis[4][5 * 24 + 8];    // [wave][i_local*24 + p]
    int wave = threadIdx.x >> 6, lane = threadIdx.x & 63;
    int gw = blockIdx.x * 4 + wave;
    int v = gw / 5, g = gw - v * 5;         // node, row-group
    if (v >= Nn) return;
    int beg = row_ptr[v], end = row_ptr[v + 1];
    if (beg < c0) beg = c0;
    if (end > c1) end = c1;
    if (beg >= end) return;

    int i0 = g * 5;
    float* wi = wis[wave];
    // fixed per-lane staging pattern: idx = lane + 64k, k<2, idx<120
    int soff[2];
    #pragma unroll
    for (int k = 0; k < 2; ++k) {
        int idx = lane + k * 64;
        int i = idx / 24, p = idx - i * 24;
        bool act = (idx < 120) && (p < 19);
        soff[k] = act ? ((i0 + i) * 25 + d_wcol[p]) : -1;
        if (idx < 120 && p >= 19) wi[idx] = 0.f;   // zero pad once (DS in-order)
    }

    int cc = lane * 2;
    float2 acc[5];
    #pragma unroll
    for (int i = 0; i < 5; ++i) acc[i] = make_float2(0.f, 0.f);

    for (int pos = beg; pos < end; ++pos) {
        int pe = perm[pos];
        const float* wp = winv + (size_t)pe * 625;
        #pragma unroll
        for (int k = 0; k < 2; ++k)
            if (soff[k] >= 0) wi[lane + k * 64] = wp[soff[k]];

        float d = edist[pe] * (1.f / 6.f);
        float d2 = d * d, d5 = d2 * d2 * d;
        float env = (d < 1.f) ? (1.f + d5 * (-21.f + 35.f * d - 15.f * d2)) : 0.f;

        const u16* yp = Yc2 + (size_t)(pos - c0) * 2432 + cc;
        float2 pv[20];
        #pragma unroll
        for (int p = 0; p < 19; ++p) {
            unsigned u = *(const unsigned*)(yp + (size_t)p * 128);
            pv[p].x = b2f((u16)(u & 0xffff)) * env;
            pv[p].y = b2f((u16)(u >> 16)) * env;
        }
        pv[19] = make_float2(0.f, 0.f);

        #pragma unroll
        for (int i = 0; i < 5; ++i) {
            float ax = 0.f, ay = 0.f;
            #pragma unroll
            for (int pb = 0; pb < 5; ++pb) {
                float4 wv = *(const float4*)&wi[i * 24 + pb * 4];
                float2 q0 = pv[pb * 4], q1 = pv[pb * 4 + 1];
                float2 q2 = pv[pb * 4 + 2], q3 = pv[pb * 4 + 3];
                ax += wv.x * q0.x + wv.y * q1.x + wv.z * q2.x + wv.w * q3.x;
                ay += wv.x * q0.y + wv.y * q1.y + wv.z * q2.y + wv.w * q3.y;
            }
            acc[i].x += ax; acc[i].y += ay;
        }
    }

    float* ob = out + (size_t)v * 3200 + (size_t)i0 * 128 + cc;
    #pragma unroll
    for (int i = 0; i < 5; ++i) {
        ob[i * 128]     += acc[i].x;      // exclusive row slice: non-atomic RMW
        ob[i * 128 + 1] += acc[i].y;
    }
}

// ---------------------------------------------------------------------------
// Counting sort by dst: histogram -> single-block scan -> scatter.
// ---------------------------------------------------------------------------
__global__ __launch_bounds__(256)
void hist_k(const int* __restrict__ eidx, const int* __restrict__ noff,
            int* __restrict__ cnt, int E)
{
    int e = blockIdx.x * 256 + threadIdx.x;
    if (e < E) atomicAdd(&cnt[eidx[E + e] - noff[0]], 1);
}

__global__ __launch_bounds__(256)
void scan_k(const int* __restrict__ cnt, int* __restrict__ row_ptr,
            int* __restrict__ ofs, int Nn)
{
    __shared__ int part[256];
    int t = threadIdx.x;
    int per = (Nn + 255) / 256;
    int beg = t * per;
    int s = 0;
    for (int i = 0; i < per; ++i) {
        int idx = beg + i;
        if (idx < Nn) s += cnt[idx];
    }
    part[t] = s;
    __syncthreads();
    for (int o = 1; o < 256; o <<= 1) {
        int v = (t >= o) ? part[t - o] : 0;
        __syncthreads();
        part[t] += v;
        __syncthreads();
    }
    int run = (t == 0) ? 0 : part[t - 1];
    for (int i = 0; i < per; ++i) {
        int idx = beg + i;
        if (idx < Nn) {
            row_ptr[idx] = run;
            ofs[idx] = run;
            run += cnt[idx];
        }
    }
    if (t == 255) row_ptr[Nn] = part[255];
}

__global__ __launch_bounds__(256)
void scat_k(const int* __restrict__ eidx, const int* __restrict__ noff,
            int* __restrict__ ofs, int* __restrict__ perm, int E)
{
    int e = blockIdx.x * 256 + threadIdx.x;
    if (e < E) {
        int v = eidx[E + e] - noff[0];
        int pos = atomicAdd(&ofs[v], 1);
        perm[pos] = e;
    }
}

// ---------------------------------------------------------------------------
// Complex-fold weight transform (fp32 -> bf16)
// ---------------------------------------------------------------------------
__global__ __launch_bounds__(256)
void wprime(const float* __restrict__ Wm, u16* __restrict__ Wp, int H, int Kin)
{
    int o = blockIdx.y;
    int k = blockIdx.x * 256 + threadIdx.x;
    if (k >= 2 * Kin) return;
    float v;
    if (k < Kin) v = Wm[(size_t)o * Kin + k];
    else {
        int k2 = k - Kin;
        v = (o < H) ? -Wm[(size_t)(o + H) * Kin + k2]
                    :  Wm[(size_t)(o - H) * Kin + k2];
    }
    Wp[(size_t)o * 2 * Kin + k] = f2b(v);
}

__global__ __launch_bounds__(256)
void cvt_w(const float* __restrict__ a, u16* __restrict__ o, int n)
{
    int i = blockIdx.x * 256 + threadIdx.x;
    if (i < n) o[i] = f2b(a[i]);
}

__global__ __launch_bounds__(256)
void zerof(float4* __restrict__ p, int n4)
{
    int i = blockIdx.x * 256 + threadIdx.x;
    if (i < n4) p[i] = make_float4(0.f, 0.f, 0.f, 0.f);
}

extern "C" void kernel_launch(void* const* d_in, const int* in_sizes, int n_in,
                              void* d_out, int out_size, void* d_ws, size_t ws_size,
                              hipStream_t stream)
{
    const float* x      = (const float*)d_in[0];
    const float* x_edge = (const float*)d_in[1];
    const float* edist  = (const float*)d_in[2];
    const float* wig    = (const float*)d_in[3];
    const float* winv   = (const float*)d_in[4];
    const float* W_r1   = (const float*)d_in[5];
    const float* b_r1   = (const float*)d_in[6];
    const float* ln_g   = (const float*)d_in[7];
    const float* ln_b   = (const float*)d_in[8];
    const float* W_r2   = (const float*)d_in[9];
    const float* b_r2   = (const float*)d_in[10];
    const float* W0_1   = (const float*)d_in[11];
    const float* b0_1   = (const float*)d_in[12];
    const float* Wm1_1  = (const float*)d_in[13];
    const float* Wm2_1  = (const float*)d_in[14];
    const float* W0_2   = (const float*)d_in[15];
    const float* b0_2   = (const float*)d_in[16];
    const float* Wm1_2  = (const float*)d_in[17];
    const float* Wm2_2  = (const float*)d_in[18];
    const int*   eidx   = (const int*)d_in[19];
    const int*   noff   = (const int*)d_in[20];
    float* out = (float*)d_out;

    const int E  = in_sizes[2];          // 50000
    const int Nn = in_sizes[0] / 3200;   // nodes: x is Nn*25*128 ELEMENTS (in_sizes are element counts)

    size_t off = 0;
    auto take = [&](size_t bytes) -> char* {
        char* p = (char*)d_ws + off;
        off += (bytes + 255) & ~(size_t)255;
        return p;
    };
    // ---- fixed: bf16 weight copies (~14.4 MB) + sort structures ----
    u16* Wr2c = (u16*)take((size_t)3072 * 128 * 2);
    u16* W01c = (u16*)take((size_t)1152 * 1280 * 2);
    u16* Wp11 = (u16*)take((size_t)1024 * 2048 * 2);
    u16* Wp21 = (u16*)take((size_t)768 * 1536 * 2);
    u16* W02c = (u16*)take((size_t)640 * 640 * 2);
    u16* Wp12 = (u16*)take((size_t)1024 * 1024 * 2);
    u16* Wp22 = (u16*)take((size_t)768 * 768 * 2);
    int  NnR  = (Nn + 3) & ~3;
    int* cnt     = (int*)take((size_t)NnR * 4);
    int* ofs     = (int*)take((size_t)NnR * 4);
    int* row_ptr = (int*)take((size_t)(Nn + 1) * 4);
    int* perm    = (int*)take((size_t)E * 4);
    size_t fixed = off;

    // ---- adaptive chunk: 22016 B/edge, capped at 12800 edges ----
    const size_t per_edge = 256 + 6144 + 9728 + 5888;
    size_t avail = (ws_size > fixed + 65536) ? (ws_size - fixed - 65536) : 0;
    long long ch = (long long)(avail / per_edge);
    if (ch > 12800) ch = 12800;
    ch &= ~255LL;
    if (ch < 256) ch = 256;
    const int CH = (int)ch;

    u16* silu_h = (u16*)take((size_t)CH * 128 * 2);
    u16* radb   = (u16*)take((size_t)CH * 3072 * 2);
    u16* xreg   = (u16*)take((size_t)CH * 4864 * 2);  // Xc1, then Xc2
    u16* yreg   = (u16*)take((size_t)CH * 2944 * 2);  // Yc1, then Yc2

    dim3 b256(256);

    cvt_w<<<1536, b256, 0, stream>>>(W_r2, Wr2c, 3072 * 128);
    cvt_w<<<5760, b256, 0, stream>>>(W0_1, W01c, 1152 * 1280);
    cvt_w<<<1600, b256, 0, stream>>>(W0_2, W02c, 640 * 640);
    wprime<<<dim3(8, 1024), b256, 0, stream>>>(Wm1_1, Wp11, 512, 1024);
    wprime<<<dim3(6,  768), b256, 0, stream>>>(Wm2_1, Wp21, 384, 768);
    wprime<<<dim3(4, 1024), b256, 0, stream>>>(Wm1_2, Wp12, 512, 512);
    wprime<<<dim3(3,  768), b256, 0, stream>>>(Wm2_2, Wp22, 384, 384);

    zerof<<<(out_size / 4 + 255) / 256, b256, 0, stream>>>((float4*)out,
                                                           out_size / 4);

    // ---- counting sort of edges by dst ----
    zerof<<<(NnR / 4 + 255) / 256, b256, 0, stream>>>((float4*)cnt, NnR / 4);
    hist_k<<<(E + 255) / 256, b256, 0, stream>>>(eidx, noff, cnt, E);
    scan_k<<<1, b256, 0, stream>>>(cnt, row_ptr, ofs, Nn);
    scat_k<<<(E + 255) / 256, b256, 0, stream>>>(eidx, noff, ofs, perm, E);

    for (int c0 = 0; c0 < E; c0 += CH) {
        int n  = (E - c0 < CH) ? (E - c0) : CH;
        int MT = (n + 127) / 128;
        int gm = 8 * ((MT + 7) / 8);

        radial1<<<n, 128, 0, stream>>>(x_edge, perm, c0, W_r1, b_r1,
                                       ln_g, ln_b, silu_h);
        gemm_bf16<<<gm * 24, b256, 0, stream>>>(silu_h, 128, Wr2c, 128, b_r2,
                                                radb, 3072, n, 24, MT, 128);

        wigner_gather<<<(n + 3) / 4, b256, 0, stream>>>(x, wig, radb, eidx,
                                                        perm, xreg, E, c0, n);

        gemm_bf16<<<gm * 9, b256, 0, stream>>>(xreg,        4864, W01c, 1280, b0_1,
                                               yreg,        2944, n, 9, MT, 1280);
        gemm_bf16<<<gm * 8, b256, 0, stream>>>(xreg + 1280, 4864, Wp11, 2048, nullptr,
                                               yreg + 1152, 2944, n, 8, MT, 2048);
        gemm_bf16<<<gm * 6, b256, 0, stream>>>(xreg + 3328, 4864, Wp21, 1536, nullptr,
                                               yreg + 2176, 2944, n, 6, MT, 1536);

        gate_combine<<<n, b256, 0, stream>>>(yreg, xreg);

        gemm_bf16<<<gm * 5, b256, 0, stream>>>(xreg,        2432, W02c,  640, b0_2,
                                               yreg,        2432, n, 5, MT, 640);
        gemm_bf16<<<gm * 8, b256, 0, stream>>>(xreg + 640,  2432, Wp12, 1024, nullptr,
                                               yreg + 640,  2432, n, 8, MT, 1024);
        gemm_bf16<<<gm * 6, b256, 0, stream>>>(xreg + 1664, 2432, Wp22,  768, nullptr,
                                               yreg + 1664, 2432, n, 6, MT, 768);

        final_node<<<(Nn * 5 + 3) / 4, b256, 0, stream>>>(yreg, winv, edist, perm,
                                                          row_ptr, out, c0, c0 + n, Nn);
    }
}

// Round 5
// 3352.696 us; speedup vs baseline: 1.3203x; 1.1120x over previous
//
#include <hip/hip_runtime.h>

typedef unsigned short u16;
typedef __bf16 bf16x8 __attribute__((ext_vector_type(8)));
typedef float f32x4 __attribute__((ext_vector_type(4)));

__device__ __forceinline__ float b2f(u16 h) {
    union { unsigned u; float f; } v; v.u = ((unsigned)h) << 16; return v.f;
}
__device__ __forceinline__ u16 f2b(float f) {
    union { float f; unsigned u; } v; v.f = f;
    unsigned r = v.u + 0x7FFF + ((v.u >> 16) & 1);
    return (u16)(r >> 16);
}
__device__ __forceinline__ float sigm(float x) { return 1.f / (1.f + __expf(-x)); }

// async global->LDS, 16 B per lane; LDS dest must be wave-uniform base (HW
// writes base + lane*16). Size arg must be a literal (16).
__device__ __forceinline__ void gload16(const u16* g, u16* l) {
    __builtin_amdgcn_global_load_lds(
        (const __attribute__((address_space(1))) unsigned int*)g,
        (__attribute__((address_space(3))) unsigned int*)l, 16, 0, 0);
}

// wcol[p] = OUT_MASK[PERM[p]] : wigner row (fwd) / wigner_inv col (bwd) for permuted slot p
__constant__ int d_wcol[19]    = {0,2,6,12,20, 3,7,13,21, 1,5,11,19, 8,14,22, 4,10,18};
// rad offset (in the 3072-wide radial vector) for permuted slot p
__constant__ int d_radbase[19] = {0,256,512,768,1024, 1280,1536,1792,2048, 1280,1536,1792,2048,
                                  2304,2560,2816, 2304,2560,2816};
// gate channel base (l-1)*128 for permuted slot p (p=0 uses silu instead)
__constant__ int d_gbase[19]   = {0, 0,128,256,384, 0,128,256,384, 0,128,256,384,
                                  128,256,384, 128,256,384};

// ---------------------------------------------------------------------------
// bf16 MFMA GEMM:  C[M,N] = A[M,K] @ B[N,K]^T (+fp32 bias),  128x128 tile.
// v2: global_load_lds(16B) staging into LINEAR LDS with XOR chunk-swizzle
// (source-side g8 = c8 ^ (row&7); same XOR on ds_read side -> 2-way banks).
// Requires N % 128 == 0 and K % 64 == 0 (all call sites satisfy this).
// ---------------------------------------------------------------------------
__global__ __launch_bounds__(256)
void gemm_bf16(const u16* __restrict__ A, int lda,
               const u16* __restrict__ B, int ldb,
               const float* __restrict__ bias,
               u16* __restrict__ C, int ldc,
               int M, int NT, int MT, int K)
{
    __shared__ u16 Asl[128 * 64];   // linear: row*64 + chunk*8 (chunk = 16B unit)
    __shared__ u16 Bsl[128 * 64];
    int w = blockIdx.x;
    int g = w & 7, q = w >> 3;
    int mt = g + 8 * (q / NT);
    int nt = q % NT;
    if (mt >= MT) return;
    int m0 = mt * 128, n0 = nt * 128;
    int tid = threadIdx.x;
    int lane = tid & 63, wave = tid >> 6;
    int wm = (wave >> 1) * 64, wn = (wave & 1) * 64;

    // staging geometry: wave covers 4 blocks of 8 rows; lane l -> row blk*8+l/8,
    // LDS chunk l%8, global chunk (l%8) ^ (row&7)  [inverse-swizzled source]
    int srow_l = lane >> 3;                 // 0..7 row within block
    int c8     = lane & 7;                  // LDS chunk (linear dest)

    f32x4 acc[4][4] = {};

    for (int k0 = 0; k0 < K; k0 += 64) {
        #pragma unroll
        for (int i = 0; i < 4; ++i) {
            int blk = wave * 4 + i;         // 16 blocks of 8 rows = 128 rows
            int row = blk * 8 + srow_l;
            int g8  = c8 ^ (row & 7);       // pre-swizzled source chunk
            int ga = m0 + row; if (ga > M - 1) ga = M - 1;   // clamp (rows >= M unused)
            gload16(A + (size_t)ga * lda + k0 + g8 * 8, &Asl[blk * 512]);
            gload16(B + (size_t)(n0 + row) * ldb + k0 + g8 * 8, &Bsl[blk * 512]);
        }
        __syncthreads();
        #pragma unroll
        for (int kk = 0; kk < 64; kk += 32) {
            bf16x8 af[4], bfr[4];
            int kc = (kk >> 3) + (lane >> 4);   // global 16B-chunk index of frag
            #pragma unroll
            for (int t = 0; t < 4; ++t) {
                int ra = wm + t * 16 + (lane & 15);
                int rb = wn + t * 16 + (lane & 15);
                af[t]  = *(const bf16x8*)&Asl[ra * 64 + (kc ^ (ra & 7)) * 8];
                bfr[t] = *(const bf16x8*)&Bsl[rb * 64 + (kc ^ (rb & 7)) * 8];
            }
            #pragma unroll
            for (int mi = 0; mi < 4; ++mi)
                #pragma unroll
                for (int ni = 0; ni < 4; ++ni)
                    acc[mi][ni] = __builtin_amdgcn_mfma_f32_16x16x32_bf16(
                        af[mi], bfr[ni], acc[mi][ni], 0, 0, 0);
        }
        __syncthreads();
    }

    #pragma unroll
    for (int ni = 0; ni < 4; ++ni) {
        int col = n0 + wn + ni * 16 + (lane & 15);
        float bv = bias ? bias[col] : 0.f;
        #pragma unroll
        for (int mi = 0; mi < 4; ++mi) {
            int rb = m0 + wm + mi * 16 + (lane >> 4) * 4;
            #pragma unroll
            for (int r = 0; r < 4; ++r) {
                int row = rb + r;
                if (row < M) C[(size_t)row * ldc + col] = f2b(acc[mi][ni][r] + bv);
            }
        }
    }
}

// ---------------------------------------------------------------------------
// Radial stage 1 (fp32 in): h = x_edge @ W_r1^T + b ; LayerNorm ; silu -> bf16
// Edge identity taken through perm (sorted-by-dst order).
// ---------------------------------------------------------------------------
__global__ __launch_bounds__(128)
void radial1(const float* __restrict__ xe, const int* __restrict__ perm,
             int c0, const float* __restrict__ W1,
             const float* __restrict__ b1, const float* __restrict__ lg,
             const float* __restrict__ lb, u16* __restrict__ sh)
{
    __shared__ float xs[128];
    __shared__ float part[4];
    int e = blockIdx.x, c = threadIdx.x;
    int pe = perm[c0 + e];
    xs[c] = xe[(size_t)pe * 128 + c];
    __syncthreads();
    float acc = 0.f;
    const float4* wr = (const float4*)(W1 + (size_t)c * 128);
    #pragma unroll
    for (int kb = 0; kb < 32; ++kb) {
        float4 v = wr[kb];
        acc += v.x * xs[kb * 4 + 0];
        acc += v.y * xs[kb * 4 + 1];
        acc += v.z * xs[kb * 4 + 2];
        acc += v.w * xs[kb * 4 + 3];
    }
    float h = acc + b1[c];
    float s = h, ss = h * h;
    #pragma unroll
    for (int o = 32; o > 0; o >>= 1) {
        s  += __shfl_down(s, o, 64);
        ss += __shfl_down(ss, o, 64);
    }
    int wv = c >> 6;
    if ((c & 63) == 0) { part[wv * 2] = s; part[wv * 2 + 1] = ss; }
    __syncthreads();
    float S = part[0] + part[2], SS = part[1] + part[3];
    float mu = S * (1.f / 128.f);
    float var = SS * (1.f / 128.f) - mu * mu;
    float hn = (h - mu) * rsqrtf(var + 1e-5f) * lg[c] + lb[c];
    sh[(size_t)e * 128 + c] = f2b(hn * sigm(hn));
}

// ---------------------------------------------------------------------------
// Gather src/dst fp32 features, apply wigner[OUT_MASK] rows in PERM order,
// scale by radial (bf16), write conv1 input Xc1 (n x 4864 bf16).
// 1 wave/edge, 4 edges/block; perm indirection (sorted-by-dst order).
// ---------------------------------------------------------------------------
__global__ __launch_bounds__(256, 4)
void wigner_gather(const float* __restrict__ x, const float* __restrict__ wig,
                   const u16* __restrict__ rad, const int* __restrict__ eidx,
                   const int* __restrict__ perm,
                   u16* __restrict__ Xc1, int E, int c0, int n)
{
    __shared__ float wgs[4][25 * 24 + 8];   // j-major: [wave][j*24 + p]
    int wave = threadIdx.x >> 6, lane = threadIdx.x & 63;
    int e = blockIdx.x * 4 + wave;
    if (e > n - 1) e = n - 1;               // tail waves redo edge n-1 (benign identical writes)
    int pe = perm[c0 + e];

    // stage wigner rows transposed to j-major (pad p to 24 for aligned b128)
    const float* wp = wig + (size_t)pe * 625;
    float* wg = wgs[wave];
    for (int i = lane; i < 600; i += 64) {
        int j = i / 24, p = i - j * 24;
        wg[i] = (p < 19) ? wp[d_wcol[p] * 25 + j] : 0.f;
    }

    int s = eidx[pe], dn = eidx[E + pe];
    const float* xbase = (lane < 32)
        ? x + (size_t)s  * 3200 + lane * 4
        : x + (size_t)dn * 3200 + (lane - 32) * 4;

    __syncthreads();

    float4 acc[20];
    #pragma unroll
    for (int p = 0; p < 20; ++p) acc[p] = make_float4(0.f, 0.f, 0.f, 0.f);

    float4 nxt = *(const float4*)xbase;
    #pragma unroll
    for (int j = 0; j < 25; ++j) {
        float4 xv = nxt;
        if (j < 24) nxt = *(const float4*)(xbase + (j + 1) * 128);
        #pragma unroll
        for (int pb = 0; pb < 5; ++pb) {
            float4 w4 = *(const float4*)&wg[j * 24 + pb * 4];
            int q = pb * 4;
            acc[q+0].x += w4.x * xv.x; acc[q+0].y += w4.x * xv.y;
            acc[q+0].z += w4.x * xv.z; acc[q+0].w += w4.x * xv.w;
            acc[q+1].x += w4.y * xv.x; acc[q+1].y += w4.y * xv.y;
            acc[q+1].z += w4.y * xv.z; acc[q+1].w += w4.y * xv.w;
            acc[q+2].x += w4.z * xv.x; acc[q+2].y += w4.z * xv.y;
            acc[q+2].z += w4.z * xv.z; acc[q+2].w += w4.z * xv.w;
            acc[q+3].x += w4.w * xv.x; acc[q+3].y += w4.w * xv.y;
            acc[q+3].z += w4.w * xv.z; acc[q+3].w += w4.w * xv.w;
        }
    }

    int c4v = lane * 4;
    const u16* rp = rad + (size_t)e * 3072;
    u16* outp = Xc1 + (size_t)e * 4864 + c4v;
    #pragma unroll
    for (int p = 0; p < 19; ++p) {
        ushort4 rv = *(const ushort4*)(rp + d_radbase[p] + c4v);
        ushort4 st;
        st.x = f2b(acc[p].x * b2f(rv.x));
        st.y = f2b(acc[p].y * b2f(rv.y));
        st.z = f2b(acc[p].z * b2f(rv.z));
        st.w = f2b(acc[p].w * b2f(rv.w));
        *(ushort4*)(outp + (size_t)p * 256) = st;
    }
}

// ---------------------------------------------------------------------------
// Gate: slot0 -> silu, slots 1..18 -> * sigmoid(extra[(l-1)*128+c]).
// ---------------------------------------------------------------------------
__global__ __launch_bounds__(256)
void gate_combine(const u16* __restrict__ Yc1, u16* __restrict__ Xc2)
{
    int e = blockIdx.x;
    const u16* yp = Yc1 + (size_t)e * 2944;
    u16* xp = Xc2 + (size_t)e * 2432;
    for (int r = threadIdx.x; r < 2432; r += 256) {
        int p = r >> 7, c = r & 127;
        float v = b2f(yp[512 + r]);
        float o;
        if (p == 0) o = v * sigm(v);
        else        o = v * sigm(b2f(yp[d_gbase[p] + c]));
        xp[r] = f2b(o);
    }
}

// ---------------------------------------------------------------------------
// Final: 5 waves per node, each owning 5 output rows (i = g*5..g*5+4).
// Edges sorted by dst; register accumulation; non-atomic RMW of exclusive
// row slice.
// ---------------------------------------------------------------------------
__global__ __launch_bounds__(256)
void final_node(const u16* __restrict__ Yc2, const float* __restrict__ winv,
                const float* __restrict__ edist, const int* __restrict__ perm,
                const int* __restrict__ row_ptr, float* __restrict__ out,
                int c0, int c1, int Nn)
{
    __shared__ float wis[4][5 * 24 + 8];    // [wave][i_local*24 + p]
    int wave = threadIdx.x >> 6, lane = threadIdx.x & 63;
    int gw = blockIdx.x * 4 + wave;
    int v = gw / 5, g = gw - v * 5;         // node, row-group
    if (v >= Nn) return;
    int beg = row_ptr[v], end = row_ptr[v + 1];
    if (beg < c0) beg = c0;
    if (end > c1) end = c1;
    if (beg >= end) return;

    int i0 = g * 5;
    float* wi = wis[wave];
    // fixed per-lane staging pattern: idx = lane + 64k, k<2, idx<120
    int soff[2];
    #pragma unroll
    for (int k = 0; k < 2; ++k) {
        int idx = lane + k * 64;
        int i = idx / 24, p = idx - i * 24;
        bool act = (idx < 120) && (p < 19);
        soff[k] = act ? ((i0 + i) * 25 + d_wcol[p]) : -1;
        if (idx < 120 && p >= 19) wi[idx] = 0.f;   // zero pad once (DS in-order)
    }

    int cc = lane * 2;
    float2 acc[5];
    #pragma unroll
    for (int i = 0; i < 5; ++i) acc[i] = make_float2(0.f, 0.f);

    for (int pos = beg; pos < end; ++pos) {
        int pe = perm[pos];
        const float* wp = winv + (size_t)pe * 625;
        #pragma unroll
        for (int k = 0; k < 2; ++k)
            if (soff[k] >= 0) wi[lane + k * 64] = wp[soff[k]];

        float d = edist[pe] * (1.f / 6.f);
        float d2 = d * d, d5 = d2 * d2 * d;
        float env = (d < 1.f) ? (1.f + d5 * (-21.f + 35.f * d - 15.f * d2)) : 0.f;

        const u16* yp = Yc2 + (size_t)(pos - c0) * 2432 + cc;
        float2 pv[20];
        #pragma unroll
        for (int p = 0; p < 19; ++p) {
            unsigned u = *(const unsigned*)(yp + (size_t)p * 128);
            pv[p].x = b2f((u16)(u & 0xffff)) * env;
            pv[p].y = b2f((u16)(u >> 16)) * env;
        }
        pv[19] = make_float2(0.f, 0.f);

        #pragma unroll
        for (int i = 0; i < 5; ++i) {
            float ax = 0.f, ay = 0.f;
            #pragma unroll
            for (int pb = 0; pb < 5; ++pb) {
                float4 wv = *(const float4*)&wi[i * 24 + pb * 4];
                float2 q0 = pv[pb * 4], q1 = pv[pb * 4 + 1];
                float2 q2 = pv[pb * 4 + 2], q3 = pv[pb * 4 + 3];
                ax += wv.x * q0.x + wv.y * q1.x + wv.z * q2.x + wv.w * q3.x;
                ay += wv.x * q0.y + wv.y * q1.y + wv.z * q2.y + wv.w * q3.y;
            }
            acc[i].x += ax; acc[i].y += ay;
        }
    }

    float* ob = out + (size_t)v * 3200 + (size_t)i0 * 128 + cc;
    #pragma unroll
    for (int i = 0; i < 5; ++i) {
        ob[i * 128]     += acc[i].x;      // exclusive row slice: non-atomic RMW
        ob[i * 128 + 1] += acc[i].y;
    }
}

// ---------------------------------------------------------------------------
// Counting sort by dst: histogram -> single-block scan -> scatter.
// ---------------------------------------------------------------------------
__global__ __launch_bounds__(256)
void hist_k(const int* __restrict__ eidx, const int* __restrict__ noff,
            int* __restrict__ cnt, int E)
{
    int e = blockIdx.x * 256 + threadIdx.x;
    if (e < E) atomicAdd(&cnt[eidx[E + e] - noff[0]], 1);
}

__global__ __launch_bounds__(256)
void scan_k(const int* __restrict__ cnt, int* __restrict__ row_ptr,
            int* __restrict__ ofs, int Nn)
{
    __shared__ int part[256];
    int t = threadIdx.x;
    int per = (Nn + 255) / 256;
    int beg = t * per;
    int s = 0;
    for (int i = 0; i < per; ++i) {
        int idx = beg + i;
        if (idx < Nn) s += cnt[idx];
    }
    part[t] = s;
    __syncthreads();
    for (int o = 1; o < 256; o <<= 1) {
        int v = (t >= o) ? part[t - o] : 0;
        __syncthreads();
        part[t] += v;
        __syncthreads();
    }
    int run = (t == 0) ? 0 : part[t - 1];
    for (int i = 0; i < per; ++i) {
        int idx = beg + i;
        if (idx < Nn) {
            row_ptr[idx] = run;
            ofs[idx] = run;
            run += cnt[idx];
        }
    }
    if (t == 255) row_ptr[Nn] = part[255];
}

__global__ __launch_bounds__(256)
void scat_k(const int* __restrict__ eidx, const int* __restrict__ noff,
            int* __restrict__ ofs, int* __restrict__ perm, int E)
{
    int e = blockIdx.x * 256 + threadIdx.x;
    if (e < E) {
        int v = eidx[E + e] - noff[0];
        int pos = atomicAdd(&ofs[v], 1);
        perm[pos] = e;
    }
}

// ---------------------------------------------------------------------------
// Complex-fold weight transform (fp32 -> bf16)
// ---------------------------------------------------------------------------
__global__ __launch_bounds__(256)
void wprime(const float* __restrict__ Wm, u16* __restrict__ Wp, int H, int Kin)
{
    int o = blockIdx.y;
    int k = blockIdx.x * 256 + threadIdx.x;
    if (k >= 2 * Kin) return;
    float v;
    if (k < Kin) v = Wm[(size_t)o * Kin + k];
    else {
        int k2 = k - Kin;
        v = (o < H) ? -Wm[(size_t)(o + H) * Kin + k2]
                    :  Wm[(size_t)(o - H) * Kin + k2];
    }
    Wp[(size_t)o * 2 * Kin + k] = f2b(v);
}

__global__ __launch_bounds__(256)
void cvt_w(const float* __restrict__ a, u16* __restrict__ o, int n)
{
    int i = blockIdx.x * 256 + threadIdx.x;
    if (i < n) o[i] = f2b(a[i]);
}

__global__ __launch_bounds__(256)
void zerof(float4* __restrict__ p, int n4)
{
    int i = blockIdx.x * 256 + threadIdx.x;
    if (i < n4) p[i] = make_float4(0.f, 0.f, 0.f, 0.f);
}

extern "C" void kernel_launch(void* const* d_in, const int* in_sizes, int n_in,
                              void* d_out, int out_size, void* d_ws, size_t ws_size,
                              hipStream_t stream)
{
    const float* x      = (const float*)d_in[0];
    const float* x_edge = (const float*)d_in[1];
    const float* edist  = (const float*)d_in[2];
    const float* wig    = (const float*)d_in[3];
    const float* winv   = (const float*)d_in[4];
    const float* W_r1   = (const float*)d_in[5];
    const float* b_r1   = (const float*)d_in[6];
    const float* ln_g   = (const float*)d_in[7];
    const float* ln_b   = (const float*)d_in[8];
    const float* W_r2   = (const float*)d_in[9];
    const float* b_r2   = (const float*)d_in[10];
    const float* W0_1   = (const float*)d_in[11];
    const float* b0_1   = (const float*)d_in[12];
    const float* Wm1_1  = (const float*)d_in[13];
    const float* Wm2_1  = (const float*)d_in[14];
    const float* W0_2   = (const float*)d_in[15];
    const float* b0_2   = (const float*)d_in[16];
    const float* Wm1_2  = (const float*)d_in[17];
    const float* Wm2_2  = (const float*)d_in[18];
    const int*   eidx   = (const int*)d_in[19];
    const int*   noff   = (const int*)d_in[20];
    float* out = (float*)d_out;

    const int E  = in_sizes[2];          // 50000
    const int Nn = in_sizes[0] / 3200;   // nodes: x is Nn*25*128 ELEMENTS (in_sizes are element counts)

    size_t off = 0;
    auto take = [&](size_t bytes) -> char* {
        char* p = (char*)d_ws + off;
        off += (bytes + 255) & ~(size_t)255;
        return p;
    };
    // ---- fixed: bf16 weight copies (~14.4 MB) + sort structures ----
    u16* Wr2c = (u16*)take((size_t)3072 * 128 * 2);
    u16* W01c = (u16*)take((size_t)1152 * 1280 * 2);
    u16* Wp11 = (u16*)take((size_t)1024 * 2048 * 2);
    u16* Wp21 = (u16*)take((size_t)768 * 1536 * 2);
    u16* W02c = (u16*)take((size_t)640 * 640 * 2);
    u16* Wp12 = (u16*)take((size_t)1024 * 1024 * 2);
    u16* Wp22 = (u16*)take((size_t)768 * 768 * 2);
    int  NnR  = (Nn + 3) & ~3;
    int* cnt     = (int*)take((size_t)NnR * 4);
    int* ofs     = (int*)take((size_t)NnR * 4);
    int* row_ptr = (int*)take((size_t)(Nn + 1) * 4);
    int* perm    = (int*)take((size_t)E * 4);
    size_t fixed = off;

    // ---- adaptive chunk: 22016 B/edge, capped at 12800 edges ----
    const size_t per_edge = 256 + 6144 + 9728 + 5888;
    size_t avail = (ws_size > fixed + 65536) ? (ws_size - fixed - 65536) : 0;
    long long ch = (long long)(avail / per_edge);
    if (ch > 12800) ch = 12800;
    ch &= ~255LL;
    if (ch < 256) ch = 256;
    const int CH = (int)ch;

    u16* silu_h = (u16*)take((size_t)CH * 128 * 2);
    u16* radb   = (u16*)take((size_t)CH * 3072 * 2);
    u16* xreg   = (u16*)take((size_t)CH * 4864 * 2);  // Xc1, then Xc2
    u16* yreg   = (u16*)take((size_t)CH * 2944 * 2);  // Yc1, then Yc2

    dim3 b256(256);

    cvt_w<<<1536, b256, 0, stream>>>(W_r2, Wr2c, 3072 * 128);
    cvt_w<<<5760, b256, 0, stream>>>(W0_1, W01c, 1152 * 1280);
    cvt_w<<<1600, b256, 0, stream>>>(W0_2, W02c, 640 * 640);
    wprime<<<dim3(8, 1024), b256, 0, stream>>>(Wm1_1, Wp11, 512, 1024);
    wprime<<<dim3(6,  768), b256, 0, stream>>>(Wm2_1, Wp21, 384, 768);
    wprime<<<dim3(4, 1024), b256, 0, stream>>>(Wm1_2, Wp12, 512, 512);
    wprime<<<dim3(3,  768), b256, 0, stream>>>(Wm2_2, Wp22, 384, 384);

    zerof<<<(out_size / 4 + 255) / 256, b256, 0, stream>>>((float4*)out,
                                                           out_size / 4);

    // ---- counting sort of edges by dst ----
    zerof<<<(NnR / 4 + 255) / 256, b256, 0, stream>>>((float4*)cnt, NnR / 4);
    hist_k<<<(E + 255) / 256, b256, 0, stream>>>(eidx, noff, cnt, E);
    scan_k<<<1, b256, 0, stream>>>(cnt, row_ptr, ofs, Nn);
    scat_k<<<(E + 255) / 256, b256, 0, stream>>>(eidx, noff, ofs, perm, E);

    for (int c0 = 0; c0 < E; c0 += CH) {
        int n  = (E - c0 < CH) ? (E - c0) : CH;
        int MT = (n + 127) / 128;
        int gm = 8 * ((MT + 7) / 8);

        radial1<<<n, 128, 0, stream>>>(x_edge, perm, c0, W_r1, b_r1,
                                       ln_g, ln_b, silu_h);
        gemm_bf16<<<gm * 24, b256, 0, stream>>>(silu_h, 128, Wr2c, 128, b_r2,
                                                radb, 3072, n, 24, MT, 128);

        wigner_gather<<<(n + 3) / 4, b256, 0, stream>>>(x, wig, radb, eidx,
                                                        perm, xreg, E, c0, n);

        gemm_bf16<<<gm * 9, b256, 0, stream>>>(xreg,        4864, W01c, 1280, b0_1,
                                               yreg,        2944, n, 9, MT, 1280);
        gemm_bf16<<<gm * 8, b256, 0, stream>>>(xreg + 1280, 4864, Wp11, 2048, nullptr,
                                               yreg + 1152, 2944, n, 8, MT, 2048);
        gemm_bf16<<<gm * 6, b256, 0, stream>>>(xreg + 3328, 4864, Wp21, 1536, nullptr,
                                               yreg + 2176, 2944, n, 6, MT, 1536);

        gate_combine<<<n, b256, 0, stream>>>(yreg, xreg);

        gemm_bf16<<<gm * 5, b256, 0, stream>>>(xreg,        2432, W02c,  640, b0_2,
                                               yreg,        2432, n, 5, MT, 640);
        gemm_bf16<<<gm * 8, b256, 0, stream>>>(xreg + 640,  2432, Wp12, 1024, nullptr,
                                               yreg + 640,  2432, n, 8, MT, 1024);
        gemm_bf16<<<gm * 6, b256, 0, stream>>>(xreg + 1664, 2432, Wp22,  768, nullptr,
                                               yreg + 1664, 2432, n, 6, MT, 768);

        final_node<<<(Nn * 5 + 3) / 4, b256, 0, stream>>>(yreg, winv, edist, perm,
                                                          row_ptr, out, c0, c0 + n, Nn);
    }
}

// Round 6
// 3307.184 us; speedup vs baseline: 1.3384x; 1.0138x over previous
//
#include <hip/hip_runtime.h>

typedef unsigned short u16;
typedef __bf16 bf16x8 __attribute__((ext_vector_type(8)));
typedef float f32x4 __attribute__((ext_vector_type(4)));

__device__ __forceinline__ float b2f(u16 h) {
    union { unsigned u; float f; } v; v.u = ((unsigned)h) << 16; return v.f;
}
__device__ __forceinline__ u16 f2b(float f) {
    union { float f; unsigned u; } v; v.f = f;
    unsigned r = v.u + 0x7FFF + ((v.u >> 16) & 1);
    return (u16)(r >> 16);
}
__device__ __forceinline__ float sigm(float x) { return 1.f / (1.f + __expf(-x)); }

// async global->LDS, 16 B per lane; LDS dest must be wave-uniform base (HW
// writes base + lane*16). Size arg must be a literal (16).
__device__ __forceinline__ void gload16(const u16* g, u16* l) {
    __builtin_amdgcn_global_load_lds(
        (const __attribute__((address_space(1))) unsigned int*)g,
        (__attribute__((address_space(3))) unsigned int*)l, 16, 0, 0);
}

// wcol[p] = OUT_MASK[PERM[p]] : wigner row (fwd) / wigner_inv col (bwd) for permuted slot p
__constant__ int d_wcol[19]    = {0,2,6,12,20, 3,7,13,21, 1,5,11,19, 8,14,22, 4,10,18};
// rad offset (in the 3072-wide radial vector) for permuted slot p
__constant__ int d_radbase[19] = {0,256,512,768,1024, 1280,1536,1792,2048, 1280,1536,1792,2048,
                                  2304,2560,2816, 2304,2560,2816};
// gate channel base (l-1)*128 for permuted slot p (p=0 uses silu instead)
__constant__ int d_gbase[19]   = {0, 0,128,256,384, 0,128,256,384, 0,128,256,384,
                                  128,256,384, 128,256,384};

// ---------------------------------------------------------------------------
// bf16 MFMA GEMM:  C[M,N] = A[M,K] @ B[N,K]^T (+fp32 bias),  128x128 tile.
// global_load_lds(16B) staging into LINEAR LDS with XOR chunk-swizzle
// (source-side g8 = c8 ^ (row&7); same XOR on ds_read side -> 2-way banks).
// Requires N % 128 == 0 and K % 64 == 0 (all call sites satisfy this).
// ---------------------------------------------------------------------------
__global__ __launch_bounds__(256)
void gemm_bf16(const u16* __restrict__ A, int lda,
               const u16* __restrict__ B, int ldb,
               const float* __restrict__ bias,
               u16* __restrict__ C, int ldc,
               int M, int NT, int MT, int K)
{
    __shared__ u16 Asl[128 * 64];   // linear: row*64 + chunk*8 (chunk = 16B unit)
    __shared__ u16 Bsl[128 * 64];
    int w = blockIdx.x;
    int g = w & 7, q = w >> 3;
    int mt = g + 8 * (q / NT);
    int nt = q % NT;
    if (mt >= MT) return;
    int m0 = mt * 128, n0 = nt * 128;
    int tid = threadIdx.x;
    int lane = tid & 63, wave = tid >> 6;
    int wm = (wave >> 1) * 64, wn = (wave & 1) * 64;

    // staging geometry: wave covers 4 blocks of 8 rows; lane l -> row blk*8+l/8,
    // LDS chunk l%8, global chunk (l%8) ^ (row&7)  [inverse-swizzled source]
    int srow_l = lane >> 3;                 // 0..7 row within block
    int c8     = lane & 7;                  // LDS chunk (linear dest)

    f32x4 acc[4][4] = {};

    for (int k0 = 0; k0 < K; k0 += 64) {
        #pragma unroll
        for (int i = 0; i < 4; ++i) {
            int blk = wave * 4 + i;         // 16 blocks of 8 rows = 128 rows
            int row = blk * 8 + srow_l;
            int g8  = c8 ^ (row & 7);       // pre-swizzled source chunk
            int ga = m0 + row; if (ga > M - 1) ga = M - 1;   // clamp (rows >= M unused)
            gload16(A + (size_t)ga * lda + k0 + g8 * 8, &Asl[blk * 512]);
            gload16(B + (size_t)(n0 + row) * ldb + k0 + g8 * 8, &Bsl[blk * 512]);
        }
        __syncthreads();
        #pragma unroll
        for (int kk = 0; kk < 64; kk += 32) {
            bf16x8 af[4], bfr[4];
            int kc = (kk >> 3) + (lane >> 4);   // global 16B-chunk index of frag
            #pragma unroll
            for (int t = 0; t < 4; ++t) {
                int ra = wm + t * 16 + (lane & 15);
                int rb = wn + t * 16 + (lane & 15);
                af[t]  = *(const bf16x8*)&Asl[ra * 64 + (kc ^ (ra & 7)) * 8];
                bfr[t] = *(const bf16x8*)&Bsl[rb * 64 + (kc ^ (rb & 7)) * 8];
            }
            #pragma unroll
            for (int mi = 0; mi < 4; ++mi)
                #pragma unroll
                for (int ni = 0; ni < 4; ++ni)
                    acc[mi][ni] = __builtin_amdgcn_mfma_f32_16x16x32_bf16(
                        af[mi], bfr[ni], acc[mi][ni], 0, 0, 0);
        }
        __syncthreads();
    }

    #pragma unroll
    for (int ni = 0; ni < 4; ++ni) {
        int col = n0 + wn + ni * 16 + (lane & 15);
        float bv = bias ? bias[col] : 0.f;
        #pragma unroll
        for (int mi = 0; mi < 4; ++mi) {
            int rb = m0 + wm + mi * 16 + (lane >> 4) * 4;
            #pragma unroll
            for (int r = 0; r < 4; ++r) {
                int row = rb + r;
                if (row < M) C[(size_t)row * ldc + col] = f2b(acc[mi][ni][r] + bv);
            }
        }
    }
}

// ---------------------------------------------------------------------------
// Radial stage 1 (fp32 in): h = x_edge @ W_r1^T + b ; LayerNorm ; silu -> bf16
// Edge identity taken through perm (sorted-by-dst order).
// ---------------------------------------------------------------------------
__global__ __launch_bounds__(128)
void radial1(const float* __restrict__ xe, const int* __restrict__ perm,
             int c0, const float* __restrict__ W1,
             const float* __restrict__ b1, const float* __restrict__ lg,
             const float* __restrict__ lb, u16* __restrict__ sh)
{
    __shared__ float xs[128];
    __shared__ float part[4];
    int e = blockIdx.x, c = threadIdx.x;
    int pe = perm[c0 + e];
    xs[c] = xe[(size_t)pe * 128 + c];
    __syncthreads();
    float acc = 0.f;
    const float4* wr = (const float4*)(W1 + (size_t)c * 128);
    #pragma unroll
    for (int kb = 0; kb < 32; ++kb) {
        float4 v = wr[kb];
        acc += v.x * xs[kb * 4 + 0];
        acc += v.y * xs[kb * 4 + 1];
        acc += v.z * xs[kb * 4 + 2];
        acc += v.w * xs[kb * 4 + 3];
    }
    float h = acc + b1[c];
    float s = h, ss = h * h;
    #pragma unroll
    for (int o = 32; o > 0; o >>= 1) {
        s  += __shfl_down(s, o, 64);
        ss += __shfl_down(ss, o, 64);
    }
    int wv = c >> 6;
    if ((c & 63) == 0) { part[wv * 2] = s; part[wv * 2 + 1] = ss; }
    __syncthreads();
    float S = part[0] + part[2], SS = part[1] + part[3];
    float mu = S * (1.f / 128.f);
    float var = SS * (1.f / 128.f) - mu * mu;
    float hn = (h - mu) * rsqrtf(var + 1e-5f) * lg[c] + lb[c];
    sh[(size_t)e * 128 + c] = f2b(hn * sigm(hn));
}

// ---------------------------------------------------------------------------
// Gather src/dst fp32 features, apply wigner[OUT_MASK] rows in PERM order,
// scale by radial (bf16), write conv1 input Xc1 (n x 4864 bf16).
// 1 wave/edge, 4 edges/block; perm indirection (sorted-by-dst order).
// v3: 4-deep x-row register prefetch, issued BEFORE the barrier so HBM
// latency hides under the wigner LDS staging (was 2-deep after barrier;
// kernel was MLP-starved: 35% HBM, 27% VALU, 37% occ).
// ---------------------------------------------------------------------------
__global__ __launch_bounds__(256, 4)
void wigner_gather(const float* __restrict__ x, const float* __restrict__ wig,
                   const u16* __restrict__ rad, const int* __restrict__ eidx,
                   const int* __restrict__ perm,
                   u16* __restrict__ Xc1, int E, int c0, int n)
{
    __shared__ float wgs[4][25 * 24 + 8];   // j-major: [wave][j*24 + p]
    int wave = threadIdx.x >> 6, lane = threadIdx.x & 63;
    int e = blockIdx.x * 4 + wave;
    if (e > n - 1) e = n - 1;               // tail waves redo edge n-1 (benign identical writes)
    int pe = perm[c0 + e];

    // stage wigner rows transposed to j-major (pad p to 24 for aligned b128)
    const float* wp = wig + (size_t)pe * 625;
    float* wg = wgs[wave];
    for (int i = lane; i < 600; i += 64) {
        int j = i / 24, p = i - j * 24;
        wg[i] = (p < 19) ? wp[d_wcol[p] * 25 + j] : 0.f;
    }

    int s = eidx[pe], dn = eidx[E + pe];
    const float* xbase = (lane < 32)
        ? x + (size_t)s  * 3200 + lane * 4
        : x + (size_t)dn * 3200 + (lane - 32) * 4;

    // 4-deep prefetch, in flight across the barrier (independent of LDS)
    float4 buf[4];
    #pragma unroll
    for (int t = 0; t < 4; ++t) buf[t] = *(const float4*)(xbase + t * 128);

    __syncthreads();

    float4 acc[20];
    #pragma unroll
    for (int p = 0; p < 20; ++p) acc[p] = make_float4(0.f, 0.f, 0.f, 0.f);

    #pragma unroll
    for (int j = 0; j < 25; ++j) {          // full unroll -> buf[j&3] static (no scratch)
        float4 xv = buf[j & 3];
        if (j + 4 < 25) buf[j & 3] = *(const float4*)(xbase + (j + 4) * 128);
        #pragma unroll
        for (int pb = 0; pb < 5; ++pb) {
            float4 w4 = *(const float4*)&wg[j * 24 + pb * 4];
            int q = pb * 4;
            acc[q+0].x += w4.x * xv.x; acc[q+0].y += w4.x * xv.y;
            acc[q+0].z += w4.x * xv.z; acc[q+0].w += w4.x * xv.w;
            acc[q+1].x += w4.y * xv.x; acc[q+1].y += w4.y * xv.y;
            acc[q+1].z += w4.y * xv.z; acc[q+1].w += w4.y * xv.w;
            acc[q+2].x += w4.z * xv.x; acc[q+2].y += w4.z * xv.y;
            acc[q+2].z += w4.z * xv.z; acc[q+2].w += w4.z * xv.w;
            acc[q+3].x += w4.w * xv.x; acc[q+3].y += w4.w * xv.y;
            acc[q+3].z += w4.w * xv.z; acc[q+3].w += w4.w * xv.w;
        }
    }

    int c4v = lane * 4;
    const u16* rp = rad + (size_t)e * 3072;
    u16* outp = Xc1 + (size_t)e * 4864 + c4v;
    #pragma unroll
    for (int p = 0; p < 19; ++p) {
        ushort4 rv = *(const ushort4*)(rp + d_radbase[p] + c4v);
        ushort4 st;
        st.x = f2b(acc[p].x * b2f(rv.x));
        st.y = f2b(acc[p].y * b2f(rv.y));
        st.z = f2b(acc[p].z * b2f(rv.z));
        st.w = f2b(acc[p].w * b2f(rv.w));
        *(ushort4*)(outp + (size_t)p * 256) = st;
    }
}

// ---------------------------------------------------------------------------
// Gate: slot0 -> silu, slots 1..18 -> * sigmoid(extra[(l-1)*128+c]).
// ---------------------------------------------------------------------------
__global__ __launch_bounds__(256)
void gate_combine(const u16* __restrict__ Yc1, u16* __restrict__ Xc2)
{
    int e = blockIdx.x;
    const u16* yp = Yc1 + (size_t)e * 2944;
    u16* xp = Xc2 + (size_t)e * 2432;
    for (int r = threadIdx.x; r < 2432; r += 256) {
        int p = r >> 7, c = r & 127;
        float v = b2f(yp[512 + r]);
        float o;
        if (p == 0) o = v * sigm(v);
        else        o = v * sigm(b2f(yp[d_gbase[p] + c]));
        xp[r] = f2b(o);
    }
}

// ---------------------------------------------------------------------------
// Final: 5 waves per node, each owning 5 output rows (i = g*5..g*5+4).
// Edges sorted by dst; register accumulation; non-atomic RMW of exclusive
// row slice.
// ---------------------------------------------------------------------------
__global__ __launch_bounds__(256)
void final_node(const u16* __restrict__ Yc2, const float* __restrict__ winv,
                const float* __restrict__ edist, const int* __restrict__ perm,
                const int* __restrict__ row_ptr, float* __restrict__ out,
                int c0, int c1, int Nn)
{
    __shared__ float wis[4][5 * 24 + 8];    // [wave][i_local*24 + p]
    int wave = threadIdx.x >> 6, lane = threadIdx.x & 63;
    int gw = blockIdx.x * 4 + wave;
    int v = gw / 5, g = gw - v * 5;         // node, row-group
    if (v >= Nn) return;
    int beg = row_ptr[v], end = row_ptr[v + 1];
    if (beg < c0) beg = c0;
    if (end > c1) end = c1;
    if (beg >= end) return;

    int i0 = g * 5;
    float* wi = wis[wave];
    // fixed per-lane staging pattern: idx = lane + 64k, k<2, idx<120
    int soff[2];
    #pragma unroll
    for (int k = 0; k < 2; ++k) {
        int idx = lane + k * 64;
        int i = idx / 24, p = idx - i * 24;
        bool act = (idx < 120) && (p < 19);
        soff[k] = act ? ((i0 + i) * 25 + d_wcol[p]) : -1;
        if (idx < 120 && p >= 19) wi[idx] = 0.f;   // zero pad once (DS in-order)
    }

    int cc = lane * 2;
    float2 acc[5];
    #pragma unroll
    for (int i = 0; i < 5; ++i) acc[i] = make_float2(0.f, 0.f);

    for (int pos = beg; pos < end; ++pos) {
        int pe = perm[pos];
        const float* wp = winv + (size_t)pe * 625;
        #pragma unroll
        for (int k = 0; k < 2; ++k)
            if (soff[k] >= 0) wi[lane + k * 64] = wp[soff[k]];

        float d = edist[pe] * (1.f / 6.f);
        float d2 = d * d, d5 = d2 * d2 * d;
        float env = (d < 1.f) ? (1.f + d5 * (-21.f + 35.f * d - 15.f * d2)) : 0.f;

        const u16* yp = Yc2 + (size_t)(pos - c0) * 2432 + cc;
        float2 pv[20];
        #pragma unroll
        for (int p = 0; p < 19; ++p) {
            unsigned u = *(const unsigned*)(yp + (size_t)p * 128);
            pv[p].x = b2f((u16)(u & 0xffff)) * env;
            pv[p].y = b2f((u16)(u >> 16)) * env;
        }
        pv[19] = make_float2(0.f, 0.f);

        #pragma unroll
        for (int i = 0; i < 5; ++i) {
            float ax = 0.f, ay = 0.f;
            #pragma unroll
            for (int pb = 0; pb < 5; ++pb) {
                float4 wv = *(const float4*)&wi[i * 24 + pb * 4];
                float2 q0 = pv[pb * 4], q1 = pv[pb * 4 + 1];
                float2 q2 = pv[pb * 4 + 2], q3 = pv[pb * 4 + 3];
                ax += wv.x * q0.x + wv.y * q1.x + wv.z * q2.x + wv.w * q3.x;
                ay += wv.x * q0.y + wv.y * q1.y + wv.z * q2.y + wv.w * q3.y;
            }
            acc[i].x += ax; acc[i].y += ay;
        }
    }

    float* ob = out + (size_t)v * 3200 + (size_t)i0 * 128 + cc;
    #pragma unroll
    for (int i = 0; i < 5; ++i) {
        ob[i * 128]     += acc[i].x;      // exclusive row slice: non-atomic RMW
        ob[i * 128 + 1] += acc[i].y;
    }
}

// ---------------------------------------------------------------------------
// Counting sort by dst: histogram -> single-block scan -> scatter.
// ---------------------------------------------------------------------------
__global__ __launch_bounds__(256)
void hist_k(const int* __restrict__ eidx, const int* __restrict__ noff,
            int* __restrict__ cnt, int E)
{
    int e = blockIdx.x * 256 + threadIdx.x;
    if (e < E) atomicAdd(&cnt[eidx[E + e] - noff[0]], 1);
}

__global__ __launch_bounds__(256)
void scan_k(const int* __restrict__ cnt, int* __restrict__ row_ptr,
            int* __restrict__ ofs, int Nn)
{
    __shared__ int part[256];
    int t = threadIdx.x;
    int per = (Nn + 255) / 256;
    int beg = t * per;
    int s = 0;
    for (int i = 0; i < per; ++i) {
        int idx = beg + i;
        if (idx < Nn) s += cnt[idx];
    }
    part[t] = s;
    __syncthreads();
    for (int o = 1; o < 256; o <<= 1) {
        int v = (t >= o) ? part[t - o] : 0;
        __syncthreads();
        part[t] += v;
        __syncthreads();
    }
    int run = (t == 0) ? 0 : part[t - 1];
    for (int i = 0; i < per; ++i) {
        int idx = beg + i;
        if (idx < Nn) {
            row_ptr[idx] = run;
            ofs[idx] = run;
            run += cnt[idx];
        }
    }
    if (t == 255) row_ptr[Nn] = part[255];
}

__global__ __launch_bounds__(256)
void scat_k(const int* __restrict__ eidx, const int* __restrict__ noff,
            int* __restrict__ ofs, int* __restrict__ perm, int E)
{
    int e = blockIdx.x * 256 + threadIdx.x;
    if (e < E) {
        int v = eidx[E + e] - noff[0];
        int pos = atomicAdd(&ofs[v], 1);
        perm[pos] = e;
    }
}

// ---------------------------------------------------------------------------
// Complex-fold weight transform (fp32 -> bf16)
// ---------------------------------------------------------------------------
__global__ __launch_bounds__(256)
void wprime(const float* __restrict__ Wm, u16* __restrict__ Wp, int H, int Kin)
{
    int o = blockIdx.y;
    int k = blockIdx.x * 256 + threadIdx.x;
    if (k >= 2 * Kin) return;
    float v;
    if (k < Kin) v = Wm[(size_t)o * Kin + k];
    else {
        int k2 = k - Kin;
        v = (o < H) ? -Wm[(size_t)(o + H) * Kin + k2]
                    :  Wm[(size_t)(o - H) * Kin + k2];
    }
    Wp[(size_t)o * 2 * Kin + k] = f2b(v);
}

__global__ __launch_bounds__(256)
void cvt_w(const float* __restrict__ a, u16* __restrict__ o, int n)
{
    int i = blockIdx.x * 256 + threadIdx.x;
    if (i < n) o[i] = f2b(a[i]);
}

__global__ __launch_bounds__(256)
void zerof(float4* __restrict__ p, int n4)
{
    int i = blockIdx.x * 256 + threadIdx.x;
    if (i < n4) p[i] = make_float4(0.f, 0.f, 0.f, 0.f);
}

extern "C" void kernel_launch(void* const* d_in, const int* in_sizes, int n_in,
                              void* d_out, int out_size, void* d_ws, size_t ws_size,
                              hipStream_t stream)
{
    const float* x      = (const float*)d_in[0];
    const float* x_edge = (const float*)d_in[1];
    const float* edist  = (const float*)d_in[2];
    const float* wig    = (const float*)d_in[3];
    const float* winv   = (const float*)d_in[4];
    const float* W_r1   = (const float*)d_in[5];
    const float* b_r1   = (const float*)d_in[6];
    const float* ln_g   = (const float*)d_in[7];
    const float* ln_b   = (const float*)d_in[8];
    const float* W_r2   = (const float*)d_in[9];
    const float* b_r2   = (const float*)d_in[10];
    const float* W0_1   = (const float*)d_in[11];
    const float* b0_1   = (const float*)d_in[12];
    const float* Wm1_1  = (const float*)d_in[13];
    const float* Wm2_1  = (const float*)d_in[14];
    const float* W0_2   = (const float*)d_in[15];
    const float* b0_2   = (const float*)d_in[16];
    const float* Wm1_2  = (const float*)d_in[17];
    const float* Wm2_2  = (const float*)d_in[18];
    const int*   eidx   = (const int*)d_in[19];
    const int*   noff   = (const int*)d_in[20];
    float* out = (float*)d_out;

    const int E  = in_sizes[2];          // 50000
    const int Nn = in_sizes[0] / 3200;   // nodes: x is Nn*25*128 ELEMENTS (in_sizes are element counts)

    size_t off = 0;
    auto take = [&](size_t bytes) -> char* {
        char* p = (char*)d_ws + off;
        off += (bytes + 255) & ~(size_t)255;
        return p;
    };
    // ---- fixed: bf16 weight copies (~14.4 MB) + sort structures ----
    u16* Wr2c = (u16*)take((size_t)3072 * 128 * 2);
    u16* W01c = (u16*)take((size_t)1152 * 1280 * 2);
    u16* Wp11 = (u16*)take((size_t)1024 * 2048 * 2);
    u16* Wp21 = (u16*)take((size_t)768 * 1536 * 2);
    u16* W02c = (u16*)take((size_t)640 * 640 * 2);
    u16* Wp12 = (u16*)take((size_t)1024 * 1024 * 2);
    u16* Wp22 = (u16*)take((size_t)768 * 768 * 2);
    int  NnR  = (Nn + 3) & ~3;
    int* cnt     = (int*)take((size_t)NnR * 4);
    int* ofs     = (int*)take((size_t)NnR * 4);
    int* row_ptr = (int*)take((size_t)(Nn + 1) * 4);
    int* perm    = (int*)take((size_t)E * 4);
    size_t fixed = off;

    // ---- adaptive chunk: 22016 B/edge; cap raised to 51200 (single chunk
    // if workspace allows -> fewer serialized dispatches) ----
    const size_t per_edge = 256 + 6144 + 9728 + 5888;
    size_t avail = (ws_size > fixed + 65536) ? (ws_size - fixed - 65536) : 0;
    long long ch = (long long)(avail / per_edge);
    if (ch > 51200) ch = 51200;
    ch &= ~255LL;
    if (ch < 256) ch = 256;
    const int CH = (int)ch;

    u16* silu_h = (u16*)take((size_t)CH * 128 * 2);
    u16* radb   = (u16*)take((size_t)CH * 3072 * 2);
    u16* xreg   = (u16*)take((size_t)CH * 4864 * 2);  // Xc1, then Xc2
    u16* yreg   = (u16*)take((size_t)CH * 2944 * 2);  // Yc1, then Yc2

    dim3 b256(256);

    cvt_w<<<1536, b256, 0, stream>>>(W_r2, Wr2c, 3072 * 128);
    cvt_w<<<5760, b256, 0, stream>>>(W0_1, W01c, 1152 * 1280);
    cvt_w<<<1600, b256, 0, stream>>>(W0_2, W02c, 640 * 640);
    wprime<<<dim3(8, 1024), b256, 0, stream>>>(Wm1_1, Wp11, 512, 1024);
    wprime<<<dim3(6,  768), b256, 0, stream>>>(Wm2_1, Wp21, 384, 768);
    wprime<<<dim3(4, 1024), b256, 0, stream>>>(Wm1_2, Wp12, 512, 512);
    wprime<<<dim3(3,  768), b256, 0, stream>>>(Wm2_2, Wp22, 384, 384);

    zerof<<<(out_size / 4 + 255) / 256, b256, 0, stream>>>((float4*)out,
                                                           out_size / 4);

    // ---- counting sort of edges by dst ----
    zerof<<<(NnR / 4 + 255) / 256, b256, 0, stream>>>((float4*)cnt, NnR / 4);
    hist_k<<<(E + 255) / 256, b256, 0, stream>>>(eidx, noff, cnt, E);
    scan_k<<<1, b256, 0, stream>>>(cnt, row_ptr, ofs, Nn);
    scat_k<<<(E + 255) / 256, b256, 0, stream>>>(eidx, noff, ofs, perm, E);

    for (int c0 = 0; c0 < E; c0 += CH) {
        int n  = (E - c0 < CH) ? (E - c0) : CH;
        int MT = (n + 127) / 128;
        int gm = 8 * ((MT + 7) / 8);

        radial1<<<n, 128, 0, stream>>>(x_edge, perm, c0, W_r1, b_r1,
                                       ln_g, ln_b, silu_h);
        gemm_bf16<<<gm * 24, b256, 0, stream>>>(silu_h, 128, Wr2c, 128, b_r2,
                                                radb, 3072, n, 24, MT, 128);

        wigner_gather<<<(n + 3) / 4, b256, 0, stream>>>(x, wig, radb, eidx,
                                                        perm, xreg, E, c0, n);

        gemm_bf16<<<gm * 9, b256, 0, stream>>>(xreg,        4864, W01c, 1280, b0_1,
                                               yreg,        2944, n, 9, MT, 1280);
        gemm_bf16<<<gm * 8, b256, 0, stream>>>(xreg + 1280, 4864, Wp11, 2048, nullptr,
                                               yreg + 1152, 2944, n, 8, MT, 2048);
        gemm_bf16<<<gm * 6, b256, 0, stream>>>(xreg + 3328, 4864, Wp21, 1536, nullptr,
                                               yreg + 2176, 2944, n, 6, MT, 1536);

        gate_combine<<<n, b256, 0, stream>>>(yreg, xreg);

        gemm_bf16<<<gm * 5, b256, 0, stream>>>(xreg,        2432, W02c,  640, b0_2,
                                               yreg,        2432, n, 5, MT, 640);
        gemm_bf16<<<gm * 8, b256, 0, stream>>>(xreg + 640,  2432, Wp12, 1024, nullptr,
                                               yreg + 640,  2432, n, 8, MT, 1024);
        gemm_bf16<<<gm * 6, b256, 0, stream>>>(xreg + 1664, 2432, Wp22,  768, nullptr,
                                               yreg + 1664, 2432, n, 6, MT, 768);

        final_node<<<(Nn * 5 + 3) / 4, b256, 0, stream>>>(yreg, winv, edist, perm,
                                                          row_ptr, out, c0, c0 + n, Nn);
    }
}